// Round 1
// baseline (1533.736 us; speedup 1.0000x reference)
//
#include <hip/hip_runtime.h>

#define N_ 6144
#define L_ 1024
#define D_ 512
#define H_ 256

typedef unsigned short u16;
typedef __attribute__((ext_vector_type(4))) float f32x4;
typedef __attribute__((ext_vector_type(8))) short s16x8;

__device__ __forceinline__ u16 f2b(float f){
  unsigned u = __float_as_uint(f);
  u += 0x7FFFu + ((u >> 16) & 1u);
  return (u16)(u >> 16);
}
__device__ __forceinline__ float b2f(u16 h){ return __uint_as_float(((unsigned)h) << 16); }
__device__ __forceinline__ unsigned fkey(float f){
  unsigned u = __float_as_uint(f);
  return (u & 0x80000000u) ? ~u : (u | 0x80000000u);
}
__device__ __forceinline__ float funkey(unsigned k){
  unsigned u = (k & 0x80000000u) ? (k & 0x7FFFFFFFu) : ~k;
  return __uint_as_float(u);
}
__device__ __forceinline__ float wave_sum(float v){
  #pragma unroll
  for(int o=32;o;o>>=1) v += __shfl_xor(v,o);
  return v;
}
__device__ __forceinline__ float wave_max(float v){
  #pragma unroll
  for(int o=32;o;o>>=1) v = fmaxf(v,__shfl_xor(v,o));
  return v;
}
__device__ __forceinline__ float wave_min(float v){
  #pragma unroll
  for(int o=32;o;o>>=1) v = fminf(v,__shfl_xor(v,o));
  return v;
}
__device__ __forceinline__ float blk_sum256(float v){
  __shared__ float sm[4];
  v = wave_sum(v);
  __syncthreads();
  if((threadIdx.x&63)==0) sm[threadIdx.x>>6]=v;
  __syncthreads();
  return sm[0]+sm[1]+sm[2]+sm[3];
}
__device__ __forceinline__ float blk_min256(float v){
  __shared__ float sm[4];
  v = wave_min(v);
  __syncthreads();
  if((threadIdx.x&63)==0) sm[threadIdx.x>>6]=v;
  __syncthreads();
  return fminf(fminf(sm[0],sm[1]),fminf(sm[2],sm[3]));
}
__device__ __forceinline__ float blk_max256(float v){
  __shared__ float sm[4];
  v = wave_max(v);
  __syncthreads();
  if((threadIdx.x&63)==0) sm[threadIdx.x>>6]=v;
  __syncthreads();
  return fmaxf(fmaxf(sm[0],sm[1]),fmaxf(sm[2],sm[3]));
}

// ---------------- GEMM: C[M,Nc] = A[M,K](bf16,rm) @ Bt[Nc,K](bf16,rm)^T ----
// MODE 0: write fp32 C.  MODE 1: write bf16 Cb + global min/max atomics.
template<int MODE>
__global__ __launch_bounds__(256) void gemm_bt(
  const u16* __restrict__ A, const u16* __restrict__ Bt,
  int M, int Nc, int K,
  float* __restrict__ C, u16* __restrict__ Cb, unsigned* __restrict__ mmx)
{
  __shared__ u16 lA[128*32];
  __shared__ u16 lB[128*32];
  const int tid = threadIdx.x;
  const int wid = tid>>6, lane = tid&63;
  const int m0 = blockIdx.y<<7, n0 = blockIdx.x<<7;
  const int wr = wid>>1, wc = wid&1;

  // staging: 256 thr x 16B = 64 rows (of 64B) per call; 2 calls per tile
  const int srow = (wid<<4) + (lane>>2);   // 0..63
  const int scol = (lane&3)<<3;            // element col 0,8,16,24
  const u16* gA0 = A  + (size_t)(m0+srow   )*K + scol;
  const u16* gA1 = A  + (size_t)(m0+srow+64)*K + scol;
  const u16* gB0 = Bt + (size_t)(n0+srow   )*K + scol;
  const u16* gB1 = Bt + (size_t)(n0+srow+64)*K + scol;

  f32x4 acc[4][4] = {};
  const int lr = lane&15, lk = (lane>>4)<<3;

  for (int k0=0;k0<K;k0+=32){
    __builtin_amdgcn_global_load_lds((__attribute__((address_space(1))) void*)(gA0+k0),
        (__attribute__((address_space(3))) void*)(lA + (wid<<9)),        16, 0, 0);
    __builtin_amdgcn_global_load_lds((__attribute__((address_space(1))) void*)(gA1+k0),
        (__attribute__((address_space(3))) void*)(lA + 2048 + (wid<<9)), 16, 0, 0);
    __builtin_amdgcn_global_load_lds((__attribute__((address_space(1))) void*)(gB0+k0),
        (__attribute__((address_space(3))) void*)(lB + (wid<<9)),        16, 0, 0);
    __builtin_amdgcn_global_load_lds((__attribute__((address_space(1))) void*)(gB1+k0),
        (__attribute__((address_space(3))) void*)(lB + 2048 + (wid<<9)), 16, 0, 0);
    __syncthreads();
    s16x8 af[4], bfr[4];
    #pragma unroll
    for(int m=0;m<4;m++) af[m]  = *(const s16x8*)(lA + ((wr<<6)+(m<<4)+lr)*32 + lk);
    #pragma unroll
    for(int n=0;n<4;n++) bfr[n] = *(const s16x8*)(lB + ((wc<<6)+(n<<4)+lr)*32 + lk);
    #pragma unroll
    for(int m=0;m<4;m++)
      #pragma unroll
      for(int n=0;n<4;n++)
        acc[m][n] = __builtin_amdgcn_mfma_f32_16x16x32_bf16(af[m], bfr[n], acc[m][n], 0,0,0);
    __syncthreads();
  }

  const int cb = n0 + (wc<<6) + lr;
  const int rb = m0 + (wr<<6) + ((lane>>4)<<2);
  if (MODE==0){
    #pragma unroll
    for(int m=0;m<4;m++)
      #pragma unroll
      for(int n=0;n<4;n++){
        f32x4 v = acc[m][n];
        #pragma unroll
        for(int e=0;e<4;e++)
          C[(size_t)(rb+(m<<4)+e)*Nc + cb+(n<<4)] = v[e];
      }
  } else {
    float tmin = 3.0e38f, tmax = -3.0e38f;
    #pragma unroll
    for(int m=0;m<4;m++)
      #pragma unroll
      for(int n=0;n<4;n++){
        f32x4 v = acc[m][n];
        #pragma unroll
        for(int e=0;e<4;e++){
          float x = v[e];
          tmin = fminf(tmin,x); tmax = fmaxf(tmax,x);
          Cb[(size_t)(rb+(m<<4)+e)*Nc + cb+(n<<4)] = f2b(x);
        }
      }
    tmin = wave_min(tmin); tmax = wave_max(tmax);
    __shared__ float rmn[4], rmx[4];
    if(lane==0){ rmn[wid]=tmin; rmx[wid]=tmax; }
    __syncthreads();
    if(tid==0){
      float mn=fminf(fminf(rmn[0],rmn[1]),fminf(rmn[2],rmn[3]));
      float mx=fmaxf(fmaxf(rmx[0],rmx[1]),fmaxf(rmx[2],rmx[3]));
      atomicMin(mmx+0, fkey(mn));
      atomicMax(mmx+1, fkey(mx));
    }
  }
}

// src [R][C] fp32 -> dst [C][R] bf16
__global__ __launch_bounds__(256) void transpose_cast(
  const float* __restrict__ src, u16* __restrict__ dst, int R, int C)
{
  __shared__ float t[32][33];
  int c0 = blockIdx.x<<5, r0 = blockIdx.y<<5;
  int tx = threadIdx.x&31, ty = threadIdx.x>>5;
  #pragma unroll
  for(int i=0;i<32;i+=8) t[ty+i][tx] = src[(size_t)(r0+ty+i)*C + c0+tx];
  __syncthreads();
  #pragma unroll
  for(int i=0;i<32;i+=8) dst[(size_t)(c0+ty+i)*R + r0+tx] = f2b(t[tx][ty+i]);
}

__global__ __launch_bounds__(256) void prep_x(const float* __restrict__ x,
  u16* __restrict__ xb, u16* __restrict__ xnb)
{
  int row = blockIdx.x, t = threadIdx.x;
  const float* p = x + (size_t)row*L_ + (t<<2);
  f32x4 v = *(const f32x4*)p;
  float ss = v[0]*v[0]+v[1]*v[1]+v[2]*v[2]+v[3]*v[3];
  float tot = blk_sum256(ss);
  float inv = 1.0f/fmaxf(sqrtf(tot), 1e-12f);
  u16* pb = xb  + (size_t)row*L_ + (t<<2);
  u16* pn = xnb + (size_t)row*L_ + (t<<2);
  #pragma unroll
  for(int k=0;k<4;k++){ pb[k]=f2b(v[k]); pn[k]=f2b(v[k]*inv); }
}

__global__ __launch_bounds__(256) void attn_epi(const float* __restrict__ A1, const float* __restrict__ B1,
  const float* __restrict__ ba, const float* __restrict__ bb,
  const float* __restrict__ wc, const float* __restrict__ bc,
  float* __restrict__ agg, float* __restrict__ s)
{
  int row = (blockIdx.x<<2) + (threadIdx.x>>6);
  int lane = threadIdx.x&63;
  f32x4 a = *(const f32x4*)(A1 + (size_t)row*H_ + (lane<<2));
  f32x4 b = *(const f32x4*)(B1 + (size_t)row*H_ + (lane<<2));
  float acc=0;
  #pragma unroll
  for(int j=0;j<4;j++){
    int h = (lane<<2)+j;
    float tv = tanhf(a[j]+ba[h]);
    float sg = 1.0f/(1.0f+expf(-(b[j]+bb[h])));
    acc += tv*sg*wc[h];
  }
  acc = wave_sum(acc);
  if(lane==0){
    float v = acc + bc[0];
    agg[row]=v;
    s[row]=1.0f/(1.0f+expf(-v));
  }
}

__global__ __launch_bounds__(256) void s_stats(const float* __restrict__ s, float* __restrict__ sc){
  int t=threadIdx.x;
  float sum=0, mn=3e38f, mx=-3e38f;
  for(int i=t;i<N_;i+=256){ float v=s[i]; sum+=v; mn=fminf(mn,v); mx=fmaxf(mx,v); }
  float S=blk_sum256(sum);
  float MN=blk_min256(mn);
  float MX=blk_max256(mx);
  if(t==0){ sc[0]=S; sc[1]=MN; sc[2]=MX; }
}

// awb[i][j] = bf16( (c1 + beta*s_i*s_j + maps_ij) / rowsum_i )
__global__ __launch_bounds__(256) void aw_write(const float* __restrict__ maps, const float* __restrict__ s,
  const float* __restrict__ sc, u16* __restrict__ awb)
{
  int i = blockIdx.x, t = threadIdx.x;
  float smin = sc[1], smax = sc[2];
  float mn = smin*smin, mx = smax*smax;
  float beta = 0.6f/(mx-mn);
  float c1 = 0.4f - beta*mn;
  float si = s[i];
  const float* mrow = maps + (size_t)i*N_;
  float part = 0;
  for(int j=t;j<N_;j+=256) part += c1 + beta*si*s[j] + mrow[j];
  float r = blk_sum256(part);
  float inv = 1.0f/fmaxf(r, 1e-12f);
  u16* orow = awb + (size_t)i*N_;
  for(int j=t;j<N_;j+=256) orow[j] = f2b((c1 + beta*si*s[j] + mrow[j])*inv);
}

// out = relu(LN(Y*rowscale + bias; g, bn)); write bf16 (+optional fp32)
__global__ __launch_bounds__(256) void ln_epi512(const float* __restrict__ Y, const float* __restrict__ ki,
  const float* __restrict__ bias, const float* __restrict__ g, const float* __restrict__ bn,
  u16* __restrict__ outb, float* __restrict__ outf)
{
  int row = (blockIdx.x<<2)+(threadIdx.x>>6);
  int lane = threadIdx.x&63;
  int c0 = lane<<3;
  const float* y = Y + (size_t)row*D_ + c0;
  float v[8];
  *(f32x4*)(v)   = *(const f32x4*)(y);
  *(f32x4*)(v+4) = *(const f32x4*)(y+4);
  float scale = ki ? (1.0f/ki[row]) : 1.0f;
  float sum=0, ssum=0;
  #pragma unroll
  for(int j=0;j<8;j++){ v[j] = v[j]*scale + bias[c0+j]; sum+=v[j]; ssum+=v[j]*v[j]; }
  sum = wave_sum(sum); ssum = wave_sum(ssum);
  float m = sum*(1.0f/D_);
  float var = ssum*(1.0f/D_) - m*m;
  float invsd = rsqrtf(var + 1e-5f);
  u16 ob[8];
  #pragma unroll
  for(int j=0;j<8;j++){
    float o = (v[j]-m)*invsd*g[c0+j] + bn[c0+j];
    o = fmaxf(o, 0.0f);
    v[j] = o;
    ob[j] = f2b(o);
  }
  *(s16x8*)(outb + (size_t)row*D_ + c0) = *(s16x8*)ob;
  if(outf){
    *(f32x4*)(outf + (size_t)row*D_ + c0)     = *(f32x4*)v;
    *(f32x4*)(outf + (size_t)row*D_ + c0 + 4) = *(f32x4*)(v+4);
  }
}

__global__ __launch_bounds__(256) void bias_cast(const float* __restrict__ Y,
  const float* __restrict__ b, u16* __restrict__ outb)
{
  size_t idx = ((size_t)blockIdx.x*256 + threadIdx.x)<<2;
  f32x4 v = *(const f32x4*)(Y+idx);
  int c = (int)(idx & (D_-1));
  #pragma unroll
  for(int k=0;k<4;k++) outb[idx+k] = f2b(v[k]+b[c+k]);
}

__global__ void init_k(unsigned* mmx){ mmx[0]=0xFFFFFFFFu; mmx[1]=0u; }

__global__ __launch_bounds__(256) void binarize(u16* __restrict__ csb,
  const unsigned* __restrict__ mmx, float* __restrict__ ki)
{
  int i = blockIdx.x, t = threadIdx.x;
  float mn = funkey(mmx[0]), mx = funkey(mmx[1]);
  float th = mn + 0.5f*(mx-mn);
  u16* row = csb + (size_t)i*N_;
  float cnt = 0;
  for(int j=t;j<N_;j+=256){
    bool on = b2f(row[j]) >= th;
    row[j] = on ? (u16)0x3F80 : (u16)0;
    cnt += on ? 1.0f : 0.0f;
  }
  float k = blk_sum256(cnt);
  if(t==0) ki[i] = k;
}

__global__ __launch_bounds__(256) void trans_z(const u16* __restrict__ csb, const float* __restrict__ agg,
  const float* __restrict__ ki, float* __restrict__ z)
{
  int i=blockIdx.x, t=threadIdx.x;
  const u16* row = csb + (size_t)i*N_;
  float d=0;
  for(int j=t;j<N_;j+=256) d += b2f(row[j])*agg[j];
  float tot = blk_sum256(d);
  if(t==0){
    float tr = tot/(ki[i]*sqrtf((float)N_));
    z[i] = 0.3f*tr + 0.7f*agg[i];
  }
}

__global__ __launch_bounds__(1024) void softmax_prep(const float* __restrict__ z,
  float* __restrict__ e, float* __restrict__ sexp)
{
  int t = threadIdx.x;
  __shared__ float sm[16];
  float mx=-3e38f;
  for(int i=t;i<N_;i+=1024) mx=fmaxf(mx,z[i]);
  mx = wave_max(mx);
  if((t&63)==0) sm[t>>6]=mx;
  __syncthreads();
  float zm = sm[0];
  #pragma unroll
  for(int w=1;w<16;w++) zm=fmaxf(zm,sm[w]);
  __syncthreads();
  float sum=0;
  for(int i=t;i<N_;i+=1024){ float ee=expf(z[i]-zm); e[i]=ee; sum+=ee; }
  sum = wave_sum(sum);
  if((t&63)==0) sm[t>>6]=sum;
  __syncthreads();
  if(t==0){ float S=0; for(int w=0;w<16;w++) S+=sm[w]; *sexp=S; }
}

__global__ __launch_bounds__(256) void pooled_partial(const float* __restrict__ e,
  const float* __restrict__ g2f, const float* __restrict__ g1f, float* __restrict__ part)
{
  int b = blockIdx.x, t = threadIdx.x;
  float a0=0,a1=0,a2=0,a3=0;
  for(int r=0;r<24;r++){
    int row = b*24+r;
    float w = e[row];
    a0 += w * g2f[(size_t)row*D_ + t];
    a1 += w * g2f[(size_t)row*D_ + t+256];
    a2 += w * g1f[(size_t)row*D_ + t];
    a3 += w * g1f[(size_t)row*D_ + t+256];
  }
  part[(size_t)b*1024 + t]      = a0;
  part[(size_t)b*1024 + t+256]  = a1;
  part[(size_t)b*1024 + t+512]  = a2;
  part[(size_t)b*1024 + t+768]  = a3;
}

__global__ __launch_bounds__(1024) void final_k(const float* __restrict__ part, const float* __restrict__ sexp,
  const float* __restrict__ lng, const float* __restrict__ lnb,
  const float* __restrict__ clsw, float* __restrict__ out)
{
  int t = threadIdx.x;
  __shared__ float red[16];
  __shared__ float smv[1024];
  __shared__ float lgs[4];
  float p=0;
  for(int b=0;b<256;b++) p += part[b*1024 + t];
  p /= sexp[0];
  float w = wave_sum(p);
  if((t&63)==0) red[t>>6]=w;
  __syncthreads();
  float tot=0;
  #pragma unroll
  for(int i2=0;i2<16;i2++) tot+=red[i2];
  float m = tot*(1.0f/1024.0f);
  __syncthreads();
  float d = p-m;
  w = wave_sum(d*d);
  if((t&63)==0) red[t>>6]=w;
  __syncthreads();
  tot=0;
  #pragma unroll
  for(int i2=0;i2<16;i2++) tot+=red[i2];
  float var = tot*(1.0f/1024.0f);
  float y = d*rsqrtf(var+1e-5f)*lng[t] + lnb[t];
  smv[t]=y;
  __syncthreads();
  if(t<4){
    float lg=0;
    for(int j=0;j<1024;j++) lg += smv[j]*clsw[j*4+t];
    lgs[t]=lg;
  }
  __syncthreads();
  if(t==0){
    float h[4];
    int am=0; float best=lgs[0];
    #pragma unroll
    for(int c2=0;c2<4;c2++){ h[c2]=1.0f/(1.0f+expf(-lgs[c2])); if(lgs[c2]>best){best=lgs[c2];am=c2;} }
    float sv=1.0f;
    #pragma unroll
    for(int c2=0;c2<4;c2++){ out[c2]=h[c2]; sv*=(1.0f-h[c2]); out[4+c2]=sv; }
    out[8]=(float)am;
  }
}

extern "C" void kernel_launch(void* const* d_in, const int* in_sizes, int n_in,
                              void* d_out, int out_size, void* d_ws, size_t ws_size,
                              hipStream_t stream)
{
  const float* x_path =(const float*)d_in[0];
  const float* maps   =(const float*)d_in[1];
  const float* nl0_w1 =(const float*)d_in[2];
  const float* nl0_b1 =(const float*)d_in[3];
  const float* nl0_g  =(const float*)d_in[4];
  const float* nl0_bn =(const float*)d_in[5];
  const float* nl0_w2 =(const float*)d_in[6];
  const float* nl0_b2 =(const float*)d_in[7];
  const float* nl1_w1 =(const float*)d_in[8];
  const float* nl1_b1 =(const float*)d_in[9];
  const float* nl1_g  =(const float*)d_in[10];
  const float* nl1_bn =(const float*)d_in[11];
  const float* nl1_w2 =(const float*)d_in[12];
  const float* nl1_b2 =(const float*)d_in[13];
  const float *gw[6], *gb[6], *gg[6], *gbn[6];   // gc0,gc1,gc2,ga0,ga1,ga2
  for(int l=0;l<6;l++){
    gw[l]  = (const float*)d_in[14+l*4+0];
    gb[l]  = (const float*)d_in[14+l*4+1];
    gg[l]  = (const float*)d_in[14+l*4+2];
    gbn[l] = (const float*)d_in[14+l*4+3];
  }
  const float* attn_wa=(const float*)d_in[38];
  const float* attn_ba=(const float*)d_in[39];
  const float* attn_wb=(const float*)d_in[40];
  const float* attn_bb=(const float*)d_in[41];
  const float* attn_wc=(const float*)d_in[42];
  const float* attn_bc=(const float*)d_in[43];
  const float* cls_w  =(const float*)d_in[44];
  const float* ln_g   =(const float*)d_in[45];
  const float* ln_b   =(const float*)d_in[46];

  char* ws=(char*)d_ws;
  size_t off=0;
  auto alc=[&](size_t b)->char*{ char* p=ws+off; off=(off+b+255)&~(size_t)255; return p; };
  u16* BIG = (u16*)alc((size_t)N_*N_*2);         // awb, then cs/binary (time-shared)
  u16* XB  = (u16*)alc((size_t)N_*L_*2);
  u16* XNB = (u16*)alc((size_t)N_*L_*2);
  u16* WT_nl0w1=(u16*)alc((size_t)D_*L_*2);
  u16* WT_nl0w2=(u16*)alc((size_t)D_*D_*2);
  u16* WT_nl1w1=(u16*)alc((size_t)D_*L_*2);
  u16* WT_nl1w2=(u16*)alc((size_t)D_*D_*2);
  u16* WT_g[6];
  for(int l=0;l<6;l++) WT_g[l]=(u16*)alc((size_t)D_*D_*2);
  u16* WT_wa=(u16*)alc((size_t)H_*L_*2);
  u16* WT_wb=(u16*)alc((size_t)H_*L_*2);
  float* Hbuf=(float*)alc((size_t)N_*D_*4);
  float* Ybuf=(float*)alc((size_t)N_*D_*4);
  u16* XWT=(u16*)alc((size_t)D_*N_*2);
  u16* XA =(u16*)alc((size_t)N_*D_*2);
  u16* XBv=(u16*)alc((size_t)N_*D_*2);
  u16* X0B=(u16*)alc((size_t)N_*D_*2);
  u16* X1B=(u16*)alc((size_t)N_*D_*2);
  float* G1F=(float*)alc((size_t)N_*D_*4);
  float* G2F=(float*)alc((size_t)N_*D_*4);
  float* PART=(float*)alc((size_t)256*1024*4);
  float* AGG=(float*)alc(N_*4);
  float* SS =(float*)alc(N_*4);
  float* KI =(float*)alc(N_*4);
  float* Z  =(float*)alc(N_*4);
  float* E  =(float*)alc(N_*4);
  float* SC =(float*)alc(256);
  unsigned* MMX=(unsigned*)alc(256);
  float* SEXP=(float*)alc(256);

  float* A1=Hbuf; float* B1=Hbuf + (size_t)N_*H_;   // attn scratch aliases Hbuf

  init_k<<<1,1,0,stream>>>(MMX);
  prep_x<<<N_,256,0,stream>>>(x_path, XB, XNB);

  transpose_cast<<<dim3(D_/32, L_/32),256,0,stream>>>(nl0_w1, WT_nl0w1, L_, D_);
  transpose_cast<<<dim3(D_/32, D_/32),256,0,stream>>>(nl0_w2, WT_nl0w2, D_, D_);
  transpose_cast<<<dim3(D_/32, L_/32),256,0,stream>>>(nl1_w1, WT_nl1w1, L_, D_);
  transpose_cast<<<dim3(D_/32, D_/32),256,0,stream>>>(nl1_w2, WT_nl1w2, D_, D_);
  for(int l=0;l<6;l++)
    transpose_cast<<<dim3(D_/32, D_/32),256,0,stream>>>(gw[l], WT_g[l], D_, D_);
  transpose_cast<<<dim3(H_/32, L_/32),256,0,stream>>>(attn_wa, WT_wa, L_, H_);
  transpose_cast<<<dim3(H_/32, L_/32),256,0,stream>>>(attn_wb, WT_wb, L_, H_);

  // gated attention -> agg, s
  gemm_bt<0><<<dim3(H_/128, N_/128),256,0,stream>>>(XB, WT_wa, N_, H_, L_, A1, nullptr, nullptr);
  gemm_bt<0><<<dim3(H_/128, N_/128),256,0,stream>>>(XB, WT_wb, N_, H_, L_, B1, nullptr, nullptr);
  attn_epi<<<N_/4,256,0,stream>>>(A1,B1,attn_ba,attn_bb,attn_wc,attn_bc,AGG,SS);
  s_stats<<<1,256,0,stream>>>(SS,SC);

  // aw adjacency (l1-normalized, bf16) into BIG
  aw_write<<<N_,256,0,stream>>>(maps,SS,SC,BIG);

  // x1 = nonlin(x; nl1)
  gemm_bt<0><<<dim3(D_/128,N_/128),256,0,stream>>>(XB, WT_nl1w1, N_,D_,L_, Hbuf, nullptr,nullptr);
  ln_epi512<<<N_/4,256,0,stream>>>(Hbuf,nullptr,nl1_b1,nl1_g,nl1_bn,XA,nullptr);
  gemm_bt<0><<<dim3(D_/128,N_/128),256,0,stream>>>(XA, WT_nl1w2, N_,D_,D_, Hbuf, nullptr,nullptr);
  bias_cast<<<(N_*D_/4)/256,256,0,stream>>>(Hbuf, nl1_b2, X1B);

  // ga chain (adjacency = BIG = awb, already row-normalized)
  {
    const u16* cur=X1B;
    for(int l=0;l<3;l++){
      int gi = 3+l; // ga0..ga2
      gemm_bt<0><<<dim3(D_/128,N_/128),256,0,stream>>>(cur, WT_g[gi], N_,D_,D_, Hbuf, nullptr,nullptr);
      transpose_cast<<<dim3(D_/32, N_/32),256,0,stream>>>(Hbuf, XWT, N_, D_);
      gemm_bt<0><<<dim3(D_/128,N_/128),256,0,stream>>>(BIG, XWT, N_,D_,N_, Ybuf, nullptr,nullptr);
      u16* nxt = (l==1)? XBv : XA;
      ln_epi512<<<N_/4,256,0,stream>>>(Ybuf, nullptr, gb[gi], gg[gi], gbn[gi], nxt, (l==2)?G2F:nullptr);
      cur = nxt;
    }
  }

  // x0 = nonlin(x; nl0)
  gemm_bt<0><<<dim3(D_/128,N_/128),256,0,stream>>>(XB, WT_nl0w1, N_,D_,L_, Hbuf, nullptr,nullptr);
  ln_epi512<<<N_/4,256,0,stream>>>(Hbuf,nullptr,nl0_b1,nl0_g,nl0_bn,XA,nullptr);
  gemm_bt<0><<<dim3(D_/128,N_/128),256,0,stream>>>(XA, WT_nl0w2, N_,D_,D_, Hbuf, nullptr,nullptr);
  bias_cast<<<(N_*D_/4)/256,256,0,stream>>>(Hbuf, nl0_b2, X0B);

  // cosine gram -> BIG (bf16) + global min/max; then binarize in place + row counts
  gemm_bt<1><<<dim3(N_/128,N_/128),256,0,stream>>>(XNB, XNB, N_,N_,L_, nullptr, BIG, MMX);
  binarize<<<N_,256,0,stream>>>(BIG, MMX, KI);

  // gc chain (adjacency = BIG binary, rowscale = 1/ki)
  {
    const u16* cur=X0B;
    for(int l=0;l<3;l++){
      int gi = l; // gc0..gc2
      gemm_bt<0><<<dim3(D_/128,N_/128),256,0,stream>>>(cur, WT_g[gi], N_,D_,D_, Hbuf, nullptr,nullptr);
      transpose_cast<<<dim3(D_/32, N_/32),256,0,stream>>>(Hbuf, XWT, N_, D_);
      gemm_bt<0><<<dim3(D_/128,N_/128),256,0,stream>>>(BIG, XWT, N_,D_,N_, Ybuf, nullptr,nullptr);
      u16* nxt = (l==1)? XBv : XA;
      ln_epi512<<<N_/4,256,0,stream>>>(Ybuf, KI, gb[gi], gg[gi], gbn[gi], nxt, (l==2)?G1F:nullptr);
      cur = nxt;
    }
  }

  // pooling + head
  trans_z<<<N_,256,0,stream>>>(BIG, AGG, KI, Z);
  softmax_prep<<<1,1024,0,stream>>>(Z,E,SEXP);
  pooled_partial<<<256,256,0,stream>>>(E,G2F,G1F,PART);
  final_k<<<1,1024,0,stream>>>(PART,SEXP,ln_g,ln_b,cls_w,(float*)d_out);

  (void)in_sizes;(void)n_in;(void)out_size;(void)ws_size;
}

// Round 2
// 1147.526 us; speedup vs baseline: 1.3366x; 1.3366x over previous
//
#include <hip/hip_runtime.h>

#define N_ 6144
#define L_ 1024
#define D_ 512
#define H_ 256

typedef unsigned short u16;
typedef __attribute__((ext_vector_type(4))) float f32x4;
typedef __attribute__((ext_vector_type(8))) short s16x8;

__device__ __forceinline__ u16 f2b(float f){
  unsigned u = __float_as_uint(f);
  u += 0x7FFFu + ((u >> 16) & 1u);
  return (u16)(u >> 16);
}
__device__ __forceinline__ float b2f(u16 h){ return __uint_as_float(((unsigned)h) << 16); }
__device__ __forceinline__ unsigned fkey(float f){
  unsigned u = __float_as_uint(f);
  return (u & 0x80000000u) ? ~u : (u | 0x80000000u);
}
__device__ __forceinline__ float funkey(unsigned k){
  unsigned u = (k & 0x80000000u) ? (k & 0x7FFFFFFFu) : ~k;
  return __uint_as_float(u);
}
__device__ __forceinline__ float wave_sum(float v){
  #pragma unroll
  for(int o=32;o;o>>=1) v += __shfl_xor(v,o);
  return v;
}
__device__ __forceinline__ float wave_max(float v){
  #pragma unroll
  for(int o=32;o;o>>=1) v = fmaxf(v,__shfl_xor(v,o));
  return v;
}
__device__ __forceinline__ float wave_min(float v){
  #pragma unroll
  for(int o=32;o;o>>=1) v = fminf(v,__shfl_xor(v,o));
  return v;
}
__device__ __forceinline__ float blk_sum256(float v){
  __shared__ float sm[4];
  v = wave_sum(v);
  __syncthreads();
  if((threadIdx.x&63)==0) sm[threadIdx.x>>6]=v;
  __syncthreads();
  return sm[0]+sm[1]+sm[2]+sm[3];
}
__device__ __forceinline__ float blk_min256(float v){
  __shared__ float sm[4];
  v = wave_min(v);
  __syncthreads();
  if((threadIdx.x&63)==0) sm[threadIdx.x>>6]=v;
  __syncthreads();
  return fminf(fminf(sm[0],sm[1]),fminf(sm[2],sm[3]));
}
__device__ __forceinline__ float blk_max256(float v){
  __shared__ float sm[4];
  v = wave_max(v);
  __syncthreads();
  if((threadIdx.x&63)==0) sm[threadIdx.x>>6]=v;
  __syncthreads();
  return fmaxf(fmaxf(sm[0],sm[1]),fmaxf(sm[2],sm[3]));
}

// ---------------- GEMM: C[M,Nc] = A[M,K](bf16,rm) @ Bt[Nc,K](bf16,rm)^T ----
// Split-K over gridDim.z: slice z accumulates K/gridDim.z into plane z of C.
// MODE 0: write fp32 C plane.  MODE 1: write bf16 Cb + global min/max atomics.
template<int MODE>
__global__ __launch_bounds__(256) void gemm_bt(
  const u16* __restrict__ A, const u16* __restrict__ Bt,
  int M, int Nc, int K,
  float* __restrict__ C, u16* __restrict__ Cb, unsigned* __restrict__ mmx)
{
  __shared__ u16 lA[128*32];
  __shared__ u16 lB[128*32];
  const int tid = threadIdx.x;
  const int wid = tid>>6, lane = tid&63;
  const int m0 = blockIdx.y<<7, n0 = blockIdx.x<<7;
  const int wr = wid>>1, wc = wid&1;

  const int Klen = K / gridDim.z;
  const int kbeg = blockIdx.z * Klen;

  // staging: 256 thr x 16B = 64 rows (of 64B) per call; 2 calls per tile
  const int srow = (wid<<4) + (lane>>2);   // 0..63
  const int scol = (lane&3)<<3;            // element col 0,8,16,24
  const u16* gA0 = A  + (size_t)(m0+srow   )*K + scol;
  const u16* gA1 = A  + (size_t)(m0+srow+64)*K + scol;
  const u16* gB0 = Bt + (size_t)(n0+srow   )*K + scol;
  const u16* gB1 = Bt + (size_t)(n0+srow+64)*K + scol;

  f32x4 acc[4][4] = {};
  const int lr = lane&15, lk = (lane>>4)<<3;

  for (int k0=kbeg;k0<kbeg+Klen;k0+=32){
    __builtin_amdgcn_global_load_lds((__attribute__((address_space(1))) void*)(gA0+k0),
        (__attribute__((address_space(3))) void*)(lA + (wid<<9)),        16, 0, 0);
    __builtin_amdgcn_global_load_lds((__attribute__((address_space(1))) void*)(gA1+k0),
        (__attribute__((address_space(3))) void*)(lA + 2048 + (wid<<9)), 16, 0, 0);
    __builtin_amdgcn_global_load_lds((__attribute__((address_space(1))) void*)(gB0+k0),
        (__attribute__((address_space(3))) void*)(lB + (wid<<9)),        16, 0, 0);
    __builtin_amdgcn_global_load_lds((__attribute__((address_space(1))) void*)(gB1+k0),
        (__attribute__((address_space(3))) void*)(lB + 2048 + (wid<<9)), 16, 0, 0);
    __syncthreads();
    s16x8 af[4], bfr[4];
    #pragma unroll
    for(int m=0;m<4;m++) af[m]  = *(const s16x8*)(lA + ((wr<<6)+(m<<4)+lr)*32 + lk);
    #pragma unroll
    for(int n=0;n<4;n++) bfr[n] = *(const s16x8*)(lB + ((wc<<6)+(n<<4)+lr)*32 + lk);
    #pragma unroll
    for(int m=0;m<4;m++)
      #pragma unroll
      for(int n=0;n<4;n++)
        acc[m][n] = __builtin_amdgcn_mfma_f32_16x16x32_bf16(af[m], bfr[n], acc[m][n], 0,0,0);
    __syncthreads();
  }

  const int cb = n0 + (wc<<6) + lr;
  const int rb = m0 + (wr<<6) + ((lane>>4)<<2);
  if (MODE==0){
    float* Cp = C + (size_t)blockIdx.z * M * Nc;
    #pragma unroll
    for(int m=0;m<4;m++)
      #pragma unroll
      for(int n=0;n<4;n++){
        f32x4 v = acc[m][n];
        #pragma unroll
        for(int e=0;e<4;e++)
          Cp[(size_t)(rb+(m<<4)+e)*Nc + cb+(n<<4)] = v[e];
      }
  } else {
    float tmin = 3.0e38f, tmax = -3.0e38f;
    #pragma unroll
    for(int m=0;m<4;m++)
      #pragma unroll
      for(int n=0;n<4;n++){
        f32x4 v = acc[m][n];
        #pragma unroll
        for(int e=0;e<4;e++){
          float x = v[e];
          tmin = fminf(tmin,x); tmax = fmaxf(tmax,x);
          Cb[(size_t)(rb+(m<<4)+e)*Nc + cb+(n<<4)] = f2b(x);
        }
      }
    tmin = wave_min(tmin); tmax = wave_max(tmax);
    __shared__ float rmn[4], rmx[4];
    if(lane==0){ rmn[wid]=tmin; rmx[wid]=tmax; }
    __syncthreads();
    if(tid==0){
      float mn=fminf(fminf(rmn[0],rmn[1]),fminf(rmn[2],rmn[3]));
      float mx=fmaxf(fmaxf(rmx[0],rmx[1]),fmaxf(rmx[2],rmx[3]));
      atomicMin(mmx+0, fkey(mn));
      atomicMax(mmx+1, fkey(mx));
    }
  }
}

// dst[C][R] bf16 = transpose( sum_p src_plane_p [R][C] fp32 )
__global__ __launch_bounds__(256) void transpose_cast(
  const float* __restrict__ src, size_t pstr, int nsp,
  u16* __restrict__ dst, int R, int C)
{
  __shared__ float t[32][33];
  int c0 = blockIdx.x<<5, r0 = blockIdx.y<<5;
  int tx = threadIdx.x&31, ty = threadIdx.x>>5;
  #pragma unroll
  for(int i=0;i<32;i+=8){
    float v = 0;
    for(int p=0;p<nsp;p++)
      v += src[(size_t)p*pstr + (size_t)(r0+ty+i)*C + c0+tx];
    t[ty+i][tx] = v;
  }
  __syncthreads();
  #pragma unroll
  for(int i=0;i<32;i+=8) dst[(size_t)(c0+ty+i)*R + r0+tx] = f2b(t[tx][ty+i]);
}

__global__ __launch_bounds__(256) void prep_x(const float* __restrict__ x,
  u16* __restrict__ xb, u16* __restrict__ xnb)
{
  int row = blockIdx.x, t = threadIdx.x;
  const float* p = x + (size_t)row*L_ + (t<<2);
  f32x4 v = *(const f32x4*)p;
  float ss = v[0]*v[0]+v[1]*v[1]+v[2]*v[2]+v[3]*v[3];
  float tot = blk_sum256(ss);
  float inv = 1.0f/fmaxf(sqrtf(tot), 1e-12f);
  u16* pb = xb  + (size_t)row*L_ + (t<<2);
  u16* pn = xnb + (size_t)row*L_ + (t<<2);
  #pragma unroll
  for(int k=0;k<4;k++){ pb[k]=f2b(v[k]); pn[k]=f2b(v[k]*inv); }
}

__global__ __launch_bounds__(256) void attn_epi(const float* __restrict__ A1, const float* __restrict__ B1,
  size_t pstr, int nsp,
  const float* __restrict__ ba, const float* __restrict__ bb,
  const float* __restrict__ wc, const float* __restrict__ bc,
  float* __restrict__ agg, float* __restrict__ s)
{
  int row = (blockIdx.x<<2) + (threadIdx.x>>6);
  int lane = threadIdx.x&63;
  f32x4 a = {0,0,0,0}, b = {0,0,0,0};
  for(int p=0;p<nsp;p++){
    a += *(const f32x4*)(A1 + (size_t)p*pstr + (size_t)row*H_ + (lane<<2));
    b += *(const f32x4*)(B1 + (size_t)p*pstr + (size_t)row*H_ + (lane<<2));
  }
  float acc=0;
  #pragma unroll
  for(int j=0;j<4;j++){
    int h = (lane<<2)+j;
    float tv = tanhf(a[j]+ba[h]);
    float sg = 1.0f/(1.0f+expf(-(b[j]+bb[h])));
    acc += tv*sg*wc[h];
  }
  acc = wave_sum(acc);
  if(lane==0){
    float v = acc + bc[0];
    agg[row]=v;
    s[row]=1.0f/(1.0f+expf(-v));
  }
}

__global__ __launch_bounds__(256) void s_stats(const float* __restrict__ s, float* __restrict__ sc){
  int t=threadIdx.x;
  float sum=0, mn=3e38f, mx=-3e38f;
  for(int i=t;i<N_;i+=256){ float v=s[i]; sum+=v; mn=fminf(mn,v); mx=fmaxf(mx,v); }
  float S=blk_sum256(sum);
  float MN=blk_min256(mn);
  float MX=blk_max256(mx);
  if(t==0){ sc[0]=S; sc[1]=MN; sc[2]=MX; }
}

// awb[i][j] = bf16( (c1 + beta*s_i*s_j + maps_ij) / rowsum_i )
__global__ __launch_bounds__(256) void aw_write(const float* __restrict__ maps, const float* __restrict__ s,
  const float* __restrict__ sc, u16* __restrict__ awb)
{
  int i = blockIdx.x, t = threadIdx.x;
  float smin = sc[1], smax = sc[2];
  float mn = smin*smin, mx = smax*smax;
  float beta = 0.6f/(mx-mn);
  float c1 = 0.4f - beta*mn;
  float si = s[i];
  const float* mrow = maps + (size_t)i*N_;
  float part = 0;
  for(int j=t;j<N_;j+=256) part += c1 + beta*si*s[j] + mrow[j];
  float r = blk_sum256(part);
  float inv = 1.0f/fmaxf(r, 1e-12f);
  u16* orow = awb + (size_t)i*N_;
  for(int j=t;j<N_;j+=256) orow[j] = f2b((c1 + beta*si*s[j] + mrow[j])*inv);
}

// out = relu(LN( (sum_p Y_p)*rowscale + bias; g, bn)); write bf16
__global__ __launch_bounds__(256) void ln_epi512(const float* __restrict__ Y, size_t pstr, int nsp,
  const float* __restrict__ ki,
  const float* __restrict__ bias, const float* __restrict__ g, const float* __restrict__ bn,
  u16* __restrict__ outb)
{
  int row = (blockIdx.x<<2)+(threadIdx.x>>6);
  int lane = threadIdx.x&63;
  int c0 = lane<<3;
  float v[8] = {0,0,0,0,0,0,0,0};
  for(int p=0;p<nsp;p++){
    const float* y = Y + (size_t)p*pstr + (size_t)row*D_ + c0;
    f32x4 u0 = *(const f32x4*)(y);
    f32x4 u1 = *(const f32x4*)(y+4);
    #pragma unroll
    for(int j=0;j<4;j++){ v[j]+=u0[j]; v[4+j]+=u1[j]; }
  }
  float scale = ki ? (1.0f/ki[row]) : 1.0f;
  float sum=0, ssum=0;
  #pragma unroll
  for(int j=0;j<8;j++){ v[j] = v[j]*scale + bias[c0+j]; sum+=v[j]; ssum+=v[j]*v[j]; }
  sum = wave_sum(sum); ssum = wave_sum(ssum);
  float m = sum*(1.0f/D_);
  float var = ssum*(1.0f/D_) - m*m;
  float invsd = rsqrtf(var + 1e-5f);
  u16 ob[8];
  #pragma unroll
  for(int j=0;j<8;j++){
    float o = (v[j]-m)*invsd*g[c0+j] + bn[c0+j];
    o = fmaxf(o, 0.0f);
    ob[j] = f2b(o);
  }
  *(s16x8*)(outb + (size_t)row*D_ + c0) = *(s16x8*)ob;
}

__global__ __launch_bounds__(256) void bias_cast(const float* __restrict__ Y, size_t pstr, int nsp,
  const float* __restrict__ b, u16* __restrict__ outb)
{
  size_t idx = ((size_t)blockIdx.x*256 + threadIdx.x)<<2;
  f32x4 v = {0,0,0,0};
  for(int p=0;p<nsp;p++) v += *(const f32x4*)(Y + (size_t)p*pstr + idx);
  int c = (int)(idx & (D_-1));
  #pragma unroll
  for(int k=0;k<4;k++) outb[idx+k] = f2b(v[k]+b[c+k]);
}

__global__ void init_k(unsigned* mmx){ mmx[0]=0xFFFFFFFFu; mmx[1]=0u; }

__global__ __launch_bounds__(256) void binarize(u16* __restrict__ csb,
  const unsigned* __restrict__ mmx, float* __restrict__ ki)
{
  int i = blockIdx.x, t = threadIdx.x;
  float mn = funkey(mmx[0]), mx = funkey(mmx[1]);
  float th = mn + 0.5f*(mx-mn);
  u16* row = csb + (size_t)i*N_;
  float cnt = 0;
  for(int j=t;j<N_;j+=256){
    bool on = b2f(row[j]) >= th;
    row[j] = on ? (u16)0x3F80 : (u16)0;
    cnt += on ? 1.0f : 0.0f;
  }
  float k = blk_sum256(cnt);
  if(t==0) ki[i] = k;
}

__global__ __launch_bounds__(256) void trans_z(const u16* __restrict__ csb, const float* __restrict__ agg,
  const float* __restrict__ ki, float* __restrict__ z)
{
  int i=blockIdx.x, t=threadIdx.x;
  const u16* row = csb + (size_t)i*N_;
  float d=0;
  for(int j=t;j<N_;j+=256) d += b2f(row[j])*agg[j];
  float tot = blk_sum256(d);
  if(t==0){
    float tr = tot/(ki[i]*sqrtf((float)N_));
    z[i] = 0.3f*tr + 0.7f*agg[i];
  }
}

__global__ __launch_bounds__(1024) void softmax_prep(const float* __restrict__ z,
  float* __restrict__ e, float* __restrict__ sexp)
{
  int t = threadIdx.x;
  __shared__ float sm[16];
  float mx=-3e38f;
  for(int i=t;i<N_;i+=1024) mx=fmaxf(mx,z[i]);
  mx = wave_max(mx);
  if((t&63)==0) sm[t>>6]=mx;
  __syncthreads();
  float zm = sm[0];
  #pragma unroll
  for(int w=1;w<16;w++) zm=fmaxf(zm,sm[w]);
  __syncthreads();
  float sum=0;
  for(int i=t;i<N_;i+=1024){ float ee=expf(z[i]-zm); e[i]=ee; sum+=ee; }
  sum = wave_sum(sum);
  if((t&63)==0) sm[t>>6]=sum;
  __syncthreads();
  if(t==0){ float S=0; for(int w=0;w<16;w++) S+=sm[w]; *sexp=S; }
}

// pooled partial sums; g2/g1 are bf16 [N,512]
__global__ __launch_bounds__(256) void pooled_partial(const float* __restrict__ e,
  const u16* __restrict__ g2b, const u16* __restrict__ g1b, float* __restrict__ part)
{
  int b = blockIdx.x, t = threadIdx.x;
  float a0=0,a1=0,a2=0,a3=0;
  for(int r=0;r<24;r++){
    int row = b*24+r;
    float w = e[row];
    a0 += w * b2f(g2b[(size_t)row*D_ + t]);
    a1 += w * b2f(g2b[(size_t)row*D_ + t+256]);
    a2 += w * b2f(g1b[(size_t)row*D_ + t]);
    a3 += w * b2f(g1b[(size_t)row*D_ + t+256]);
  }
  part[(size_t)b*1024 + t]      = a0;
  part[(size_t)b*1024 + t+256]  = a1;
  part[(size_t)b*1024 + t+512]  = a2;
  part[(size_t)b*1024 + t+768]  = a3;
}

__global__ __launch_bounds__(1024) void final_k(const float* __restrict__ part, const float* __restrict__ sexp,
  const float* __restrict__ lng, const float* __restrict__ lnb,
  const float* __restrict__ clsw, float* __restrict__ out)
{
  int t = threadIdx.x;
  __shared__ float red[16];
  __shared__ float smv[1024];
  __shared__ float lgs[4];
  float p=0;
  for(int b=0;b<256;b++) p += part[b*1024 + t];
  p /= sexp[0];
  float w = wave_sum(p);
  if((t&63)==0) red[t>>6]=w;
  __syncthreads();
  float tot=0;
  #pragma unroll
  for(int i2=0;i2<16;i2++) tot+=red[i2];
  float m = tot*(1.0f/1024.0f);
  __syncthreads();
  float d = p-m;
  w = wave_sum(d*d);
  if((t&63)==0) red[t>>6]=w;
  __syncthreads();
  tot=0;
  #pragma unroll
  for(int i2=0;i2<16;i2++) tot+=red[i2];
  float var = tot*(1.0f/1024.0f);
  float y = d*rsqrtf(var+1e-5f)*lng[t] + lnb[t];
  smv[t]=y;
  __syncthreads();
  if(t<4){
    float lg=0;
    for(int j=0;j<1024;j++) lg += smv[j]*clsw[j*4+t];
    lgs[t]=lg;
  }
  __syncthreads();
  if(t==0){
    float h[4];
    int am=0; float best=lgs[0];
    #pragma unroll
    for(int c2=0;c2<4;c2++){ h[c2]=1.0f/(1.0f+expf(-lgs[c2])); if(lgs[c2]>best){best=lgs[c2];am=c2;} }
    float sv=1.0f;
    #pragma unroll
    for(int c2=0;c2<4;c2++){ out[c2]=h[c2]; sv*=(1.0f-h[c2]); out[4+c2]=sv; }
    out[8]=(float)am;
  }
}

extern "C" void kernel_launch(void* const* d_in, const int* in_sizes, int n_in,
                              void* d_out, int out_size, void* d_ws, size_t ws_size,
                              hipStream_t stream)
{
  const float* x_path =(const float*)d_in[0];
  const float* maps   =(const float*)d_in[1];
  const float* nl0_w1 =(const float*)d_in[2];
  const float* nl0_b1 =(const float*)d_in[3];
  const float* nl0_g  =(const float*)d_in[4];
  const float* nl0_bn =(const float*)d_in[5];
  const float* nl0_w2 =(const float*)d_in[6];
  const float* nl0_b2 =(const float*)d_in[7];
  const float* nl1_w1 =(const float*)d_in[8];
  const float* nl1_b1 =(const float*)d_in[9];
  const float* nl1_g  =(const float*)d_in[10];
  const float* nl1_bn =(const float*)d_in[11];
  const float* nl1_w2 =(const float*)d_in[12];
  const float* nl1_b2 =(const float*)d_in[13];
  const float *gw[6], *gb[6], *gg[6], *gbn[6];   // gc0,gc1,gc2,ga0,ga1,ga2
  for(int l=0;l<6;l++){
    gw[l]  = (const float*)d_in[14+l*4+0];
    gb[l]  = (const float*)d_in[14+l*4+1];
    gg[l]  = (const float*)d_in[14+l*4+2];
    gbn[l] = (const float*)d_in[14+l*4+3];
  }
  const float* attn_wa=(const float*)d_in[38];
  const float* attn_ba=(const float*)d_in[39];
  const float* attn_wb=(const float*)d_in[40];
  const float* attn_bb=(const float*)d_in[41];
  const float* attn_wc=(const float*)d_in[42];
  const float* attn_bc=(const float*)d_in[43];
  const float* cls_w  =(const float*)d_in[44];
  const float* ln_g   =(const float*)d_in[45];
  const float* ln_b   =(const float*)d_in[46];

  char* ws=(char*)d_ws;
  size_t off=0;
  auto alc=[&](size_t b)->char*{ char* p=ws+off; off=(off+b+255)&~(size_t)255; return p; };
  u16* BIG = (u16*)alc((size_t)N_*N_*2);         // awb, then cs/binary (time-shared)
  u16* XB  = (u16*)alc((size_t)N_*L_*2);
  u16* XNB = (u16*)alc((size_t)N_*L_*2);
  u16* WT_nl0w1=(u16*)alc((size_t)D_*L_*2);
  u16* WT_nl0w2=(u16*)alc((size_t)D_*D_*2);
  u16* WT_nl1w1=(u16*)alc((size_t)D_*L_*2);
  u16* WT_nl1w2=(u16*)alc((size_t)D_*D_*2);
  u16* WT_g[6];
  for(int l=0;l<6;l++) WT_g[l]=(u16*)alc((size_t)D_*D_*2);
  u16* WT_wa=(u16*)alc((size_t)H_*L_*2);
  u16* WT_wb=(u16*)alc((size_t)H_*L_*2);
  const int SK = 4;                               // split-K factor
  float* SP = (float*)alc((size_t)SK*N_*D_*4);    // split-K fp32 planes
  u16* XWT=(u16*)alc((size_t)D_*N_*2);
  u16* XA =(u16*)alc((size_t)N_*D_*2);
  u16* XBv=(u16*)alc((size_t)N_*D_*2);
  u16* X0B=(u16*)alc((size_t)N_*D_*2);
  u16* X1B=(u16*)alc((size_t)N_*D_*2);
  float* PART=(float*)alc((size_t)256*1024*4);
  float* AGG=(float*)alc(N_*4);
  float* SS =(float*)alc(N_*4);
  float* KI =(float*)alc(N_*4);
  float* Z  =(float*)alc(N_*4);
  float* E  =(float*)alc(N_*4);
  float* SC =(float*)alc(256);
  unsigned* MMX=(unsigned*)alc(256);
  float* SEXP=(float*)alc(256);

  const size_t PS_D = (size_t)N_*D_;
  const size_t PS_H = (size_t)N_*H_;
  float* A1 = SP;                    // 4 planes of [N,H]
  float* B1 = SP + (size_t)SK*PS_H;  // 4 planes of [N,H]

  init_k<<<1,1,0,stream>>>(MMX);
  prep_x<<<N_,256,0,stream>>>(x_path, XB, XNB);

  transpose_cast<<<dim3(D_/32, L_/32),256,0,stream>>>(nl0_w1, 0,1, WT_nl0w1, L_, D_);
  transpose_cast<<<dim3(D_/32, D_/32),256,0,stream>>>(nl0_w2, 0,1, WT_nl0w2, D_, D_);
  transpose_cast<<<dim3(D_/32, L_/32),256,0,stream>>>(nl1_w1, 0,1, WT_nl1w1, L_, D_);
  transpose_cast<<<dim3(D_/32, D_/32),256,0,stream>>>(nl1_w2, 0,1, WT_nl1w2, D_, D_);
  for(int l=0;l<6;l++)
    transpose_cast<<<dim3(D_/32, D_/32),256,0,stream>>>(gw[l], 0,1, WT_g[l], D_, D_);
  transpose_cast<<<dim3(H_/32, L_/32),256,0,stream>>>(attn_wa, 0,1, WT_wa, L_, H_);
  transpose_cast<<<dim3(H_/32, L_/32),256,0,stream>>>(attn_wb, 0,1, WT_wb, L_, H_);

  // gated attention -> agg, s
  gemm_bt<0><<<dim3(H_/128, N_/128, SK),256,0,stream>>>(XB, WT_wa, N_, H_, L_, A1, nullptr, nullptr);
  gemm_bt<0><<<dim3(H_/128, N_/128, SK),256,0,stream>>>(XB, WT_wb, N_, H_, L_, B1, nullptr, nullptr);
  attn_epi<<<N_/4,256,0,stream>>>(A1,B1,PS_H,SK,attn_ba,attn_bb,attn_wc,attn_bc,AGG,SS);
  s_stats<<<1,256,0,stream>>>(SS,SC);

  // aw adjacency (l1-normalized, bf16) into BIG
  aw_write<<<N_,256,0,stream>>>(maps,SS,SC,BIG);

  // x1 = nonlin(x; nl1)
  gemm_bt<0><<<dim3(D_/128,N_/128,SK),256,0,stream>>>(XB, WT_nl1w1, N_,D_,L_, SP, nullptr,nullptr);
  ln_epi512<<<N_/4,256,0,stream>>>(SP,PS_D,SK,nullptr,nl1_b1,nl1_g,nl1_bn,XA);
  gemm_bt<0><<<dim3(D_/128,N_/128,SK),256,0,stream>>>(XA, WT_nl1w2, N_,D_,D_, SP, nullptr,nullptr);
  bias_cast<<<(N_*D_/4)/256,256,0,stream>>>(SP,PS_D,SK, nl1_b2, X1B);

  // ga chain (adjacency = BIG = awb, already row-normalized)
  {
    const u16* cur=X1B;
    for(int l=0;l<3;l++){
      int gi = 3+l; // ga0..ga2
      gemm_bt<0><<<dim3(D_/128,N_/128,SK),256,0,stream>>>(cur, WT_g[gi], N_,D_,D_, SP, nullptr,nullptr);
      transpose_cast<<<dim3(D_/32, N_/32),256,0,stream>>>(SP, PS_D, SK, XWT, N_, D_);
      gemm_bt<0><<<dim3(D_/128,N_/128,SK),256,0,stream>>>(BIG, XWT, N_,D_,N_, SP, nullptr,nullptr);
      u16* nxt = (l==0)? XA : (l==1)? XBv : X1B;
      ln_epi512<<<N_/4,256,0,stream>>>(SP,PS_D,SK, nullptr, gb[gi], gg[gi], gbn[gi], nxt);
      cur = nxt;
    }
  }

  // x0 = nonlin(x; nl0)
  gemm_bt<0><<<dim3(D_/128,N_/128,SK),256,0,stream>>>(XB, WT_nl0w1, N_,D_,L_, SP, nullptr,nullptr);
  ln_epi512<<<N_/4,256,0,stream>>>(SP,PS_D,SK,nullptr,nl0_b1,nl0_g,nl0_bn,XA);
  gemm_bt<0><<<dim3(D_/128,N_/128,SK),256,0,stream>>>(XA, WT_nl0w2, N_,D_,D_, SP, nullptr,nullptr);
  bias_cast<<<(N_*D_/4)/256,256,0,stream>>>(SP,PS_D,SK, nl0_b2, X0B);

  // cosine gram -> BIG (bf16) + global min/max; then binarize in place + row counts
  gemm_bt<1><<<dim3(N_/128,N_/128,1),256,0,stream>>>(XNB, XNB, N_,N_,L_, nullptr, BIG, MMX);
  binarize<<<N_,256,0,stream>>>(BIG, MMX, KI);

  // gc chain (adjacency = BIG binary, rowscale = 1/ki)
  {
    const u16* cur=X0B;
    for(int l=0;l<3;l++){
      int gi = l; // gc0..gc2
      gemm_bt<0><<<dim3(D_/128,N_/128,SK),256,0,stream>>>(cur, WT_g[gi], N_,D_,D_, SP, nullptr,nullptr);
      transpose_cast<<<dim3(D_/32, N_/32),256,0,stream>>>(SP, PS_D, SK, XWT, N_, D_);
      gemm_bt<0><<<dim3(D_/128,N_/128,SK),256,0,stream>>>(BIG, XWT, N_,D_,N_, SP, nullptr,nullptr);
      u16* nxt = (l==0)? XA : (l==1)? XBv : X0B;
      ln_epi512<<<N_/4,256,0,stream>>>(SP,PS_D,SK, KI, gb[gi], gg[gi], gbn[gi], nxt);
      cur = nxt;
    }
  }

  // pooling + head
  trans_z<<<N_,256,0,stream>>>(BIG, AGG, KI, Z);
  softmax_prep<<<1,1024,0,stream>>>(Z,E,SEXP);
  pooled_partial<<<256,256,0,stream>>>(E,X1B,X0B,PART);
  final_k<<<1,1024,0,stream>>>(PART,SEXP,ln_g,ln_b,cls_w,(float*)d_out);

  (void)in_sizes;(void)n_in;(void)out_size;(void)ws_size;
}

// Round 3
// 991.575 us; speedup vs baseline: 1.5468x; 1.1573x over previous
//
#include <hip/hip_runtime.h>

#define N_ 6144
#define L_ 1024
#define D_ 512
#define H_ 256

typedef unsigned short u16;
typedef __attribute__((ext_vector_type(4))) float f32x4;
typedef __attribute__((ext_vector_type(8))) short s16x8;
typedef __attribute__((ext_vector_type(4))) short s16x4;

__device__ __forceinline__ u16 f2b(float f){
  unsigned u = __float_as_uint(f);
  u += 0x7FFFu + ((u >> 16) & 1u);
  return (u16)(u >> 16);
}
__device__ __forceinline__ float b2f(u16 h){ return __uint_as_float(((unsigned)h) << 16); }
__device__ __forceinline__ unsigned fkey(float f){
  unsigned u = __float_as_uint(f);
  return (u & 0x80000000u) ? ~u : (u | 0x80000000u);
}
__device__ __forceinline__ float funkey(unsigned k){
  unsigned u = (k & 0x80000000u) ? (k & 0x7FFFFFFFu) : ~k;
  return __uint_as_float(u);
}
__device__ __forceinline__ float wave_sum(float v){
  #pragma unroll
  for(int o=32;o;o>>=1) v += __shfl_xor(v,o);
  return v;
}
__device__ __forceinline__ float wave_max(float v){
  #pragma unroll
  for(int o=32;o;o>>=1) v = fmaxf(v,__shfl_xor(v,o));
  return v;
}
__device__ __forceinline__ float wave_min(float v){
  #pragma unroll
  for(int o=32;o;o>>=1) v = fminf(v,__shfl_xor(v,o));
  return v;
}
__device__ __forceinline__ float blk_sum256(float v){
  __shared__ float sm[4];
  v = wave_sum(v);
  __syncthreads();
  if((threadIdx.x&63)==0) sm[threadIdx.x>>6]=v;
  __syncthreads();
  return sm[0]+sm[1]+sm[2]+sm[3];
}
__device__ __forceinline__ float blk_min256(float v){
  __shared__ float sm[4];
  v = wave_min(v);
  __syncthreads();
  if((threadIdx.x&63)==0) sm[threadIdx.x>>6]=v;
  __syncthreads();
  return fminf(fminf(sm[0],sm[1]),fminf(sm[2],sm[3]));
}
__device__ __forceinline__ float blk_max256(float v){
  __shared__ float sm[4];
  v = wave_max(v);
  __syncthreads();
  if((threadIdx.x&63)==0) sm[threadIdx.x>>6]=v;
  __syncthreads();
  return fmaxf(fmaxf(sm[0],sm[1]),fmaxf(sm[2],sm[3]));
}

// ---------------- GEMM: C[M,Nc] = A[M,K](bf16,rm) @ Bt[Nc,K](bf16,rm)^T ----
// 2-phase double-buffered LDS staging (prefetch next K-tile before compute).
// Split-K over gridDim.z: slice z accumulates K/gridDim.z into bf16 plane z.
// XCD-chunked tile swizzle within each z-slice (requires gx*gy % 8 == 0).
// MODE 0: write bf16 plane.  MODE 1: write bf16 Cb + global min/max atomics.
#define STG(buf,k0) do{ \
  __builtin_amdgcn_global_load_lds((__attribute__((address_space(1))) void*)(gA0+(k0)), (__attribute__((address_space(3))) void*)(lA[buf] + (wid<<9)),        16, 0, 0); \
  __builtin_amdgcn_global_load_lds((__attribute__((address_space(1))) void*)(gA1+(k0)), (__attribute__((address_space(3))) void*)(lA[buf] + 2048 + (wid<<9)), 16, 0, 0); \
  __builtin_amdgcn_global_load_lds((__attribute__((address_space(1))) void*)(gB0+(k0)), (__attribute__((address_space(3))) void*)(lB[buf] + (wid<<9)),        16, 0, 0); \
  __builtin_amdgcn_global_load_lds((__attribute__((address_space(1))) void*)(gB1+(k0)), (__attribute__((address_space(3))) void*)(lB[buf] + 2048 + (wid<<9)), 16, 0, 0); \
}while(0)

template<int MODE>
__global__ __launch_bounds__(256) void gemm_bt(
  const u16* __restrict__ A, const u16* __restrict__ Bt,
  int M, int Nc, int K,
  u16* __restrict__ Cb, unsigned* __restrict__ mmx)
{
  __shared__ u16 lA[2][128*32];
  __shared__ u16 lB[2][128*32];
  const int tid = threadIdx.x;
  const int wid = tid>>6, lane = tid&63;

  // XCD-chunked swizzle of the (x,y) tile space within this z-slice.
  // Linear dispatch id round-robins over 8 XCDs; chunking gives each XCD a
  // contiguous tile range so same-row tiles share that XCD's L2 A-panel.
  const int gx = gridDim.x;
  int lid = blockIdx.y*gx + blockIdx.x;
  const int nwg = gx*gridDim.y;
  if ((nwg & 7) == 0) {
    const int chunk = nwg >> 3;
    lid = (lid & 7)*chunk + (lid >> 3);
  }
  const int m0 = (lid/gx)<<7, n0 = (lid%gx)<<7;
  const int wr = wid>>1, wc = wid&1;

  const int Klen = K / gridDim.z;
  const int kbeg = blockIdx.z * Klen;

  // staging: 256 thr x 16B = 64 rows (of 64B) per call; 2 calls per operand
  const int srow = (wid<<4) + (lane>>2);   // 0..63
  const int scol = (lane&3)<<3;            // element col 0,8,16,24
  const u16* gA0 = A  + (size_t)(m0+srow   )*K + scol;
  const u16* gA1 = A  + (size_t)(m0+srow+64)*K + scol;
  const u16* gB0 = Bt + (size_t)(n0+srow   )*K + scol;
  const u16* gB1 = Bt + (size_t)(n0+srow+64)*K + scol;

  f32x4 acc[4][4] = {};
  const int lr = lane&15, lk = (lane>>4)<<3;

  const int NIT = Klen>>5;
  STG(0, kbeg);
  __syncthreads();                       // vmcnt(0) drain + barrier
  for (int it=0; it<NIT; ++it){
    const int cur = it&1;
    if (it+1 < NIT) STG(cur^1, kbeg + ((it+1)<<5));   // prefetch next tile
    s16x8 af[4], bfr[4];
    #pragma unroll
    for(int m=0;m<4;m++) af[m]  = *(const s16x8*)(lA[cur] + ((wr<<6)+(m<<4)+lr)*32 + lk);
    #pragma unroll
    for(int n=0;n<4;n++) bfr[n] = *(const s16x8*)(lB[cur] + ((wc<<6)+(n<<4)+lr)*32 + lk);
    #pragma unroll
    for(int m=0;m<4;m++)
      #pragma unroll
      for(int n=0;n<4;n++)
        acc[m][n] = __builtin_amdgcn_mfma_f32_16x16x32_bf16(af[m], bfr[n], acc[m][n], 0,0,0);
    __syncthreads();                     // next tile staged + all reads done
  }

  const int cb = n0 + (wc<<6) + lr;
  const int rb = m0 + (wr<<6) + ((lane>>4)<<2);
  if (MODE==0){
    u16* Cp = Cb + (size_t)blockIdx.z * M * Nc;
    #pragma unroll
    for(int m=0;m<4;m++)
      #pragma unroll
      for(int n=0;n<4;n++){
        f32x4 v = acc[m][n];
        #pragma unroll
        for(int e=0;e<4;e++)
          Cp[(size_t)(rb+(m<<4)+e)*Nc + cb+(n<<4)] = f2b(v[e]);
      }
  } else {
    float tmin = 3.0e38f, tmax = -3.0e38f;
    #pragma unroll
    for(int m=0;m<4;m++)
      #pragma unroll
      for(int n=0;n<4;n++){
        f32x4 v = acc[m][n];
        #pragma unroll
        for(int e=0;e<4;e++){
          float x = v[e];
          tmin = fminf(tmin,x); tmax = fmaxf(tmax,x);
          Cb[(size_t)(rb+(m<<4)+e)*Nc + cb+(n<<4)] = f2b(x);
        }
      }
    tmin = wave_min(tmin); tmax = wave_max(tmax);
    __shared__ float rmn[4], rmx[4];
    if(lane==0){ rmn[wid]=tmin; rmx[wid]=tmax; }
    __syncthreads();
    if(tid==0){
      float mn=fminf(fminf(rmn[0],rmn[1]),fminf(rmn[2],rmn[3]));
      float mx=fmaxf(fmaxf(rmx[0],rmx[1]),fmaxf(rmx[2],rmx[3]));
      atomicMin(mmx+0, fkey(mn));
      atomicMax(mmx+1, fkey(mx));
    }
  }
}

// src [R][C] fp32 -> dst [C][R] bf16   (weight prep)
__global__ __launch_bounds__(256) void transpose_cast(
  const float* __restrict__ src, u16* __restrict__ dst, int R, int C)
{
  __shared__ float t[32][33];
  int c0 = blockIdx.x<<5, r0 = blockIdx.y<<5;
  int tx = threadIdx.x&31, ty = threadIdx.x>>5;
  #pragma unroll
  for(int i=0;i<32;i+=8) t[ty+i][tx] = src[(size_t)(r0+ty+i)*C + c0+tx];
  __syncthreads();
  #pragma unroll
  for(int i=0;i<32;i+=8) dst[(size_t)(c0+ty+i)*R + r0+tx] = f2b(t[tx][ty+i]);
}

// dst[C][R] bf16 = transpose( sum_p bf16_plane_p [R][C] )
__global__ __launch_bounds__(256) void transpose_sum_bf(
  const u16* __restrict__ src, size_t pstr, int nsp,
  u16* __restrict__ dst, int R, int C)
{
  __shared__ float t[32][33];
  int c0 = blockIdx.x<<5, r0 = blockIdx.y<<5;
  int tx = threadIdx.x&31, ty = threadIdx.x>>5;
  #pragma unroll
  for(int i=0;i<32;i+=8){
    float v = 0;
    for(int p=0;p<nsp;p++)
      v += b2f(src[(size_t)p*pstr + (size_t)(r0+ty+i)*C + c0+tx]);
    t[ty+i][tx] = v;
  }
  __syncthreads();
  #pragma unroll
  for(int i=0;i<32;i+=8) dst[(size_t)(c0+ty+i)*R + r0+tx] = f2b(t[tx][ty+i]);
}

__global__ __launch_bounds__(256) void prep_x(const float* __restrict__ x,
  u16* __restrict__ xb, u16* __restrict__ xnb)
{
  int row = blockIdx.x, t = threadIdx.x;
  const float* p = x + (size_t)row*L_ + (t<<2);
  f32x4 v = *(const f32x4*)p;
  float ss = v[0]*v[0]+v[1]*v[1]+v[2]*v[2]+v[3]*v[3];
  float tot = blk_sum256(ss);
  float inv = 1.0f/fmaxf(sqrtf(tot), 1e-12f);
  u16* pb = xb  + (size_t)row*L_ + (t<<2);
  u16* pn = xnb + (size_t)row*L_ + (t<<2);
  #pragma unroll
  for(int k=0;k<4;k++){ pb[k]=f2b(v[k]); pn[k]=f2b(v[k]*inv); }
}

__global__ __launch_bounds__(256) void attn_epi(const u16* __restrict__ A1, const u16* __restrict__ B1,
  size_t pstr, int nsp,
  const float* __restrict__ ba, const float* __restrict__ bb,
  const float* __restrict__ wc, const float* __restrict__ bc,
  float* __restrict__ agg, float* __restrict__ s)
{
  int row = (blockIdx.x<<2) + (threadIdx.x>>6);
  int lane = threadIdx.x&63;
  float a[4]={0,0,0,0}, b[4]={0,0,0,0};
  for(int p=0;p<nsp;p++){
    s16x4 ua = *(const s16x4*)(A1 + (size_t)p*pstr + (size_t)row*H_ + (lane<<2));
    s16x4 ub = *(const s16x4*)(B1 + (size_t)p*pstr + (size_t)row*H_ + (lane<<2));
    #pragma unroll
    for(int j=0;j<4;j++){ a[j]+=b2f((u16)ua[j]); b[j]+=b2f((u16)ub[j]); }
  }
  float acc=0;
  #pragma unroll
  for(int j=0;j<4;j++){
    int h = (lane<<2)+j;
    float tv = tanhf(a[j]+ba[h]);
    float sg = 1.0f/(1.0f+expf(-(b[j]+bb[h])));
    acc += tv*sg*wc[h];
  }
  acc = wave_sum(acc);
  if(lane==0){
    float v = acc + bc[0];
    agg[row]=v;
    s[row]=1.0f/(1.0f+expf(-v));
  }
}

__global__ __launch_bounds__(256) void s_stats(const float* __restrict__ s, float* __restrict__ sc){
  int t=threadIdx.x;
  float sum=0, mn=3e38f, mx=-3e38f;
  for(int i=t;i<N_;i+=256){ float v=s[i]; sum+=v; mn=fminf(mn,v); mx=fmaxf(mx,v); }
  float S=blk_sum256(sum);
  float MN=blk_min256(mn);
  float MX=blk_max256(mx);
  if(t==0){ sc[0]=S; sc[1]=MN; sc[2]=MX; }
}

// awb[i][j] = bf16( (c1 + beta*s_i*s_j + maps_ij) / rowsum_i )
__global__ __launch_bounds__(256) void aw_write(const float* __restrict__ maps, const float* __restrict__ s,
  const float* __restrict__ sc, u16* __restrict__ awb)
{
  int i = blockIdx.x, t = threadIdx.x;
  float smin = sc[1], smax = sc[2];
  float mn = smin*smin, mx = smax*smax;
  float beta = 0.6f/(mx-mn);
  float c1 = 0.4f - beta*mn;
  float si = s[i];
  const float* mrow = maps + (size_t)i*N_;
  float part = 0;
  for(int j=t;j<N_;j+=256) part += c1 + beta*si*s[j] + mrow[j];
  float r = blk_sum256(part);
  float inv = 1.0f/fmaxf(r, 1e-12f);
  u16* orow = awb + (size_t)i*N_;
  for(int j=t;j<N_;j+=256) orow[j] = f2b((c1 + beta*si*s[j] + mrow[j])*inv);
}

// out = relu(LN( (sum_p Y_p)*rowscale + bias; g, bn)); planes are bf16
__global__ __launch_bounds__(256) void ln_epi512(const u16* __restrict__ Y, size_t pstr, int nsp,
  const float* __restrict__ ki,
  const float* __restrict__ bias, const float* __restrict__ g, const float* __restrict__ bn,
  u16* __restrict__ outb)
{
  int row = (blockIdx.x<<2)+(threadIdx.x>>6);
  int lane = threadIdx.x&63;
  int c0 = lane<<3;
  float v[8] = {0,0,0,0,0,0,0,0};
  for(int p=0;p<nsp;p++){
    s16x8 u = *(const s16x8*)(Y + (size_t)p*pstr + (size_t)row*D_ + c0);
    #pragma unroll
    for(int j=0;j<8;j++) v[j] += b2f((u16)u[j]);
  }
  float scale = ki ? (1.0f/ki[row]) : 1.0f;
  float sum=0, ssum=0;
  #pragma unroll
  for(int j=0;j<8;j++){ v[j] = v[j]*scale + bias[c0+j]; sum+=v[j]; ssum+=v[j]*v[j]; }
  sum = wave_sum(sum); ssum = wave_sum(ssum);
  float m = sum*(1.0f/D_);
  float var = ssum*(1.0f/D_) - m*m;
  float invsd = rsqrtf(var + 1e-5f);
  u16 ob[8];
  #pragma unroll
  for(int j=0;j<8;j++){
    float o = (v[j]-m)*invsd*g[c0+j] + bn[c0+j];
    o = fmaxf(o, 0.0f);
    ob[j] = f2b(o);
  }
  *(s16x8*)(outb + (size_t)row*D_ + c0) = *(s16x8*)ob;
}

__global__ __launch_bounds__(256) void bias_cast(const u16* __restrict__ Y, size_t pstr, int nsp,
  const float* __restrict__ b, u16* __restrict__ outb)
{
  size_t idx = ((size_t)blockIdx.x*256 + threadIdx.x)<<3;
  float v[8] = {0,0,0,0,0,0,0,0};
  for(int p=0;p<nsp;p++){
    s16x8 u = *(const s16x8*)(Y + (size_t)p*pstr + idx);
    #pragma unroll
    for(int j=0;j<8;j++) v[j] += b2f((u16)u[j]);
  }
  int c = (int)(idx & (D_-1));
  u16 ob[8];
  #pragma unroll
  for(int k=0;k<8;k++) ob[k] = f2b(v[k]+b[c+k]);
  *(s16x8*)(outb+idx) = *(s16x8*)ob;
}

__global__ void init_k(unsigned* mmx){ mmx[0]=0xFFFFFFFFu; mmx[1]=0u; }

__global__ __launch_bounds__(256) void binarize(u16* __restrict__ csb,
  const unsigned* __restrict__ mmx, float* __restrict__ ki)
{
  int i = blockIdx.x, t = threadIdx.x;
  float mn = funkey(mmx[0]), mx = funkey(mmx[1]);
  float th = mn + 0.5f*(mx-mn);
  u16* row = csb + (size_t)i*N_;
  float cnt = 0;
  for(int j=t;j<N_;j+=256){
    bool on = b2f(row[j]) >= th;
    row[j] = on ? (u16)0x3F80 : (u16)0;
    cnt += on ? 1.0f : 0.0f;
  }
  float k = blk_sum256(cnt);
  if(t==0) ki[i] = k;
}

__global__ __launch_bounds__(256) void trans_z(const u16* __restrict__ csb, const float* __restrict__ agg,
  const float* __restrict__ ki, float* __restrict__ z)
{
  int i=blockIdx.x, t=threadIdx.x;
  const u16* row = csb + (size_t)i*N_;
  float d=0;
  for(int j=t;j<N_;j+=256) d += b2f(row[j])*agg[j];
  float tot = blk_sum256(d);
  if(t==0){
    float tr = tot/(ki[i]*sqrtf((float)N_));
    z[i] = 0.3f*tr + 0.7f*agg[i];
  }
}

__global__ __launch_bounds__(1024) void softmax_prep(const float* __restrict__ z,
  float* __restrict__ e, float* __restrict__ sexp)
{
  int t = threadIdx.x;
  __shared__ float sm[16];
  float mx=-3e38f;
  for(int i=t;i<N_;i+=1024) mx=fmaxf(mx,z[i]);
  mx = wave_max(mx);
  if((t&63)==0) sm[t>>6]=mx;
  __syncthreads();
  float zm = sm[0];
  #pragma unroll
  for(int w=1;w<16;w++) zm=fmaxf(zm,sm[w]);
  __syncthreads();
  float sum=0;
  for(int i=t;i<N_;i+=1024){ float ee=expf(z[i]-zm); e[i]=ee; sum+=ee; }
  sum = wave_sum(sum);
  if((t&63)==0) sm[t>>6]=sum;
  __syncthreads();
  if(t==0){ float S=0; for(int w=0;w<16;w++) S+=sm[w]; *sexp=S; }
}

// pooled partial sums; g2/g1 are bf16 [N,512]
__global__ __launch_bounds__(256) void pooled_partial(const float* __restrict__ e,
  const u16* __restrict__ g2b, const u16* __restrict__ g1b, float* __restrict__ part)
{
  int b = blockIdx.x, t = threadIdx.x;
  float a0=0,a1=0,a2=0,a3=0;
  for(int r=0;r<24;r++){
    int row = b*24+r;
    float w = e[row];
    a0 += w * b2f(g2b[(size_t)row*D_ + t]);
    a1 += w * b2f(g2b[(size_t)row*D_ + t+256]);
    a2 += w * b2f(g1b[(size_t)row*D_ + t]);
    a3 += w * b2f(g1b[(size_t)row*D_ + t+256]);
  }
  part[(size_t)b*1024 + t]      = a0;
  part[(size_t)b*1024 + t+256]  = a1;
  part[(size_t)b*1024 + t+512]  = a2;
  part[(size_t)b*1024 + t+768]  = a3;
}

__global__ __launch_bounds__(1024) void final_k(const float* __restrict__ part, const float* __restrict__ sexp,
  const float* __restrict__ lng, const float* __restrict__ lnb,
  const float* __restrict__ clsw, float* __restrict__ out)
{
  int t = threadIdx.x;
  __shared__ float red[16];
  __shared__ float smv[1024];
  __shared__ float lgs[4];
  float p=0;
  for(int b=0;b<256;b++) p += part[b*1024 + t];
  p /= sexp[0];
  float w = wave_sum(p);
  if((t&63)==0) red[t>>6]=w;
  __syncthreads();
  float tot=0;
  #pragma unroll
  for(int i2=0;i2<16;i2++) tot+=red[i2];
  float m = tot*(1.0f/1024.0f);
  __syncthreads();
  float d = p-m;
  w = wave_sum(d*d);
  if((t&63)==0) red[t>>6]=w;
  __syncthreads();
  tot=0;
  #pragma unroll
  for(int i2=0;i2<16;i2++) tot+=red[i2];
  float var = tot*(1.0f/1024.0f);
  float y = d*rsqrtf(var+1e-5f)*lng[t] + lnb[t];
  smv[t]=y;
  __syncthreads();
  if(t<4){
    float lg=0;
    for(int j=0;j<1024;j++) lg += smv[j]*clsw[j*4+t];
    lgs[t]=lg;
  }
  __syncthreads();
  if(t==0){
    float h[4];
    int am=0; float best=lgs[0];
    #pragma unroll
    for(int c2=0;c2<4;c2++){ h[c2]=1.0f/(1.0f+expf(-lgs[c2])); if(lgs[c2]>best){best=lgs[c2];am=c2;} }
    float sv=1.0f;
    #pragma unroll
    for(int c2=0;c2<4;c2++){ out[c2]=h[c2]; sv*=(1.0f-h[c2]); out[4+c2]=sv; }
    out[8]=(float)am;
  }
}

extern "C" void kernel_launch(void* const* d_in, const int* in_sizes, int n_in,
                              void* d_out, int out_size, void* d_ws, size_t ws_size,
                              hipStream_t stream)
{
  const float* x_path =(const float*)d_in[0];
  const float* maps   =(const float*)d_in[1];
  const float* nl0_w1 =(const float*)d_in[2];
  const float* nl0_b1 =(const float*)d_in[3];
  const float* nl0_g  =(const float*)d_in[4];
  const float* nl0_bn =(const float*)d_in[5];
  const float* nl0_w2 =(const float*)d_in[6];
  const float* nl0_b2 =(const float*)d_in[7];
  const float* nl1_w1 =(const float*)d_in[8];
  const float* nl1_b1 =(const float*)d_in[9];
  const float* nl1_g  =(const float*)d_in[10];
  const float* nl1_bn =(const float*)d_in[11];
  const float* nl1_w2 =(const float*)d_in[12];
  const float* nl1_b2 =(const float*)d_in[13];
  const float *gw[6], *gb[6], *gg[6], *gbn[6];   // gc0,gc1,gc2,ga0,ga1,ga2
  for(int l=0;l<6;l++){
    gw[l]  = (const float*)d_in[14+l*4+0];
    gb[l]  = (const float*)d_in[14+l*4+1];
    gg[l]  = (const float*)d_in[14+l*4+2];
    gbn[l] = (const float*)d_in[14+l*4+3];
  }
  const float* attn_wa=(const float*)d_in[38];
  const float* attn_ba=(const float*)d_in[39];
  const float* attn_wb=(const float*)d_in[40];
  const float* attn_bb=(const float*)d_in[41];
  const float* attn_wc=(const float*)d_in[42];
  const float* attn_bc=(const float*)d_in[43];
  const float* cls_w  =(const float*)d_in[44];
  const float* ln_g   =(const float*)d_in[45];
  const float* ln_b   =(const float*)d_in[46];

  char* ws=(char*)d_ws;
  size_t off=0;
  auto alc=[&](size_t b)->char*{ char* p=ws+off; off=(off+b+255)&~(size_t)255; return p; };
  u16* BIG = (u16*)alc((size_t)N_*N_*2);         // awb, then cs/binary (time-shared)
  u16* XB  = (u16*)alc((size_t)N_*L_*2);
  u16* XNB = (u16*)alc((size_t)N_*L_*2);
  u16* WT_nl0w1=(u16*)alc((size_t)D_*L_*2);
  u16* WT_nl0w2=(u16*)alc((size_t)D_*D_*2);
  u16* WT_nl1w1=(u16*)alc((size_t)D_*L_*2);
  u16* WT_nl1w2=(u16*)alc((size_t)D_*D_*2);
  u16* WT_g[6];
  for(int l=0;l<6;l++) WT_g[l]=(u16*)alc((size_t)D_*D_*2);
  u16* WT_wa=(u16*)alc((size_t)H_*L_*2);
  u16* WT_wb=(u16*)alc((size_t)H_*L_*2);
  const int SK = 4;                               // split-K factor
  u16* SP = (u16*)alc((size_t)SK*N_*D_*2);        // split-K bf16 planes
  u16* XWT=(u16*)alc((size_t)D_*N_*2);
  u16* XA =(u16*)alc((size_t)N_*D_*2);
  u16* XBv=(u16*)alc((size_t)N_*D_*2);
  u16* X0B=(u16*)alc((size_t)N_*D_*2);
  u16* X1B=(u16*)alc((size_t)N_*D_*2);
  float* PART=(float*)alc((size_t)256*1024*4);
  float* AGG=(float*)alc(N_*4);
  float* SS =(float*)alc(N_*4);
  float* KI =(float*)alc(N_*4);
  float* Z  =(float*)alc(N_*4);
  float* E  =(float*)alc(N_*4);
  float* SC =(float*)alc(256);
  unsigned* MMX=(unsigned*)alc(256);
  float* SEXP=(float*)alc(256);

  const size_t PS_D = (size_t)N_*D_;
  const size_t PS_H = (size_t)N_*H_;
  u16* A1 = SP;                      // SK planes of [N,H]
  u16* B1 = SP + (size_t)SK*PS_H;    // SK planes of [N,H]

  init_k<<<1,1,0,stream>>>(MMX);
  prep_x<<<N_,256,0,stream>>>(x_path, XB, XNB);

  transpose_cast<<<dim3(D_/32, L_/32),256,0,stream>>>(nl0_w1, WT_nl0w1, L_, D_);
  transpose_cast<<<dim3(D_/32, D_/32),256,0,stream>>>(nl0_w2, WT_nl0w2, D_, D_);
  transpose_cast<<<dim3(D_/32, L_/32),256,0,stream>>>(nl1_w1, WT_nl1w1, L_, D_);
  transpose_cast<<<dim3(D_/32, D_/32),256,0,stream>>>(nl1_w2, WT_nl1w2, D_, D_);
  for(int l=0;l<6;l++)
    transpose_cast<<<dim3(D_/32, D_/32),256,0,stream>>>(gw[l], WT_g[l], D_, D_);
  transpose_cast<<<dim3(H_/32, L_/32),256,0,stream>>>(attn_wa, WT_wa, L_, H_);
  transpose_cast<<<dim3(H_/32, L_/32),256,0,stream>>>(attn_wb, WT_wb, L_, H_);

  // gated attention -> agg, s
  gemm_bt<0><<<dim3(H_/128, N_/128, SK),256,0,stream>>>(XB, WT_wa, N_, H_, L_, A1, nullptr);
  gemm_bt<0><<<dim3(H_/128, N_/128, SK),256,0,stream>>>(XB, WT_wb, N_, H_, L_, B1, nullptr);
  attn_epi<<<N_/4,256,0,stream>>>(A1,B1,PS_H,SK,attn_ba,attn_bb,attn_wc,attn_bc,AGG,SS);
  s_stats<<<1,256,0,stream>>>(SS,SC);

  // aw adjacency (l1-normalized, bf16) into BIG
  aw_write<<<N_,256,0,stream>>>(maps,SS,SC,BIG);

  // x1 = nonlin(x; nl1)
  gemm_bt<0><<<dim3(D_/128,N_/128,SK),256,0,stream>>>(XB, WT_nl1w1, N_,D_,L_, SP, nullptr);
  ln_epi512<<<N_/4,256,0,stream>>>(SP,PS_D,SK,nullptr,nl1_b1,nl1_g,nl1_bn,XA);
  gemm_bt<0><<<dim3(D_/128,N_/128,SK),256,0,stream>>>(XA, WT_nl1w2, N_,D_,D_, SP, nullptr);
  bias_cast<<<(N_*D_/8)/256,256,0,stream>>>(SP,PS_D,SK, nl1_b2, X1B);

  // ga chain (adjacency = BIG = awb, already row-normalized)
  {
    const u16* cur=X1B;
    for(int l=0;l<3;l++){
      int gi = 3+l; // ga0..ga2
      gemm_bt<0><<<dim3(D_/128,N_/128,SK),256,0,stream>>>(cur, WT_g[gi], N_,D_,D_, SP, nullptr);
      transpose_sum_bf<<<dim3(D_/32, N_/32),256,0,stream>>>(SP, PS_D, SK, XWT, N_, D_);
      gemm_bt<0><<<dim3(D_/128,N_/128,SK),256,0,stream>>>(BIG, XWT, N_,D_,N_, SP, nullptr);
      u16* nxt = (l==0)? XA : (l==1)? XBv : X1B;
      ln_epi512<<<N_/4,256,0,stream>>>(SP,PS_D,SK, nullptr, gb[gi], gg[gi], gbn[gi], nxt);
      cur = nxt;
    }
  }

  // x0 = nonlin(x; nl0)
  gemm_bt<0><<<dim3(D_/128,N_/128,SK),256,0,stream>>>(XB, WT_nl0w1, N_,D_,L_, SP, nullptr);
  ln_epi512<<<N_/4,256,0,stream>>>(SP,PS_D,SK,nullptr,nl0_b1,nl0_g,nl0_bn,XA);
  gemm_bt<0><<<dim3(D_/128,N_/128,SK),256,0,stream>>>(XA, WT_nl0w2, N_,D_,D_, SP, nullptr);
  bias_cast<<<(N_*D_/8)/256,256,0,stream>>>(SP,PS_D,SK, nl0_b2, X0B);

  // cosine gram -> BIG (bf16) + global min/max; then binarize in place + row counts
  gemm_bt<1><<<dim3(N_/128,N_/128,1),256,0,stream>>>(XNB, XNB, N_,N_,L_, BIG, MMX);
  binarize<<<N_,256,0,stream>>>(BIG, MMX, KI);

  // gc chain (adjacency = BIG binary, rowscale = 1/ki)
  {
    const u16* cur=X0B;
    for(int l=0;l<3;l++){
      int gi = l; // gc0..gc2
      gemm_bt<0><<<dim3(D_/128,N_/128,SK),256,0,stream>>>(cur, WT_g[gi], N_,D_,D_, SP, nullptr);
      transpose_sum_bf<<<dim3(D_/32, N_/32),256,0,stream>>>(SP, PS_D, SK, XWT, N_, D_);
      gemm_bt<0><<<dim3(D_/128,N_/128,SK),256,0,stream>>>(BIG, XWT, N_,D_,N_, SP, nullptr);
      u16* nxt = (l==0)? XA : (l==1)? XBv : X0B;
      ln_epi512<<<N_/4,256,0,stream>>>(SP,PS_D,SK, KI, gb[gi], gg[gi], gbn[gi], nxt);
      cur = nxt;
    }
  }

  // pooling + head
  trans_z<<<N_,256,0,stream>>>(BIG, AGG, KI, Z);
  softmax_prep<<<1,1024,0,stream>>>(Z,E,SEXP);
  pooled_partial<<<256,256,0,stream>>>(E,X1B,X0B,PART);
  final_k<<<1,1024,0,stream>>>(PART,SEXP,ln_g,ln_b,cls_w,(float*)d_out);

  (void)in_sizes;(void)n_in;(void)out_size;(void)ws_size;
}

// Round 4
// 914.861 us; speedup vs baseline: 1.6765x; 1.0839x over previous
//
#include <hip/hip_runtime.h>

#define N_ 6144
#define L_ 1024
#define D_ 512
#define H_ 256

typedef unsigned short u16;
typedef __attribute__((ext_vector_type(4))) float f32x4;
typedef __attribute__((ext_vector_type(8))) short s16x8;
typedef __attribute__((ext_vector_type(4))) short s16x4;

__device__ __forceinline__ u16 f2b(float f){
  unsigned u = __float_as_uint(f);
  u += 0x7FFFu + ((u >> 16) & 1u);
  return (u16)(u >> 16);
}
__device__ __forceinline__ float b2f(u16 h){ return __uint_as_float(((unsigned)h) << 16); }
__device__ __forceinline__ unsigned fkey(float f){
  unsigned u = __float_as_uint(f);
  return (u & 0x80000000u) ? ~u : (u | 0x80000000u);
}
__device__ __forceinline__ float funkey(unsigned k){
  unsigned u = (k & 0x80000000u) ? (k & 0x7FFFFFFFu) : ~k;
  return __uint_as_float(u);
}
__device__ __forceinline__ float wave_sum(float v){
  #pragma unroll
  for(int o=32;o;o>>=1) v += __shfl_xor(v,o);
  return v;
}
__device__ __forceinline__ float wave_max(float v){
  #pragma unroll
  for(int o=32;o;o>>=1) v = fmaxf(v,__shfl_xor(v,o));
  return v;
}
__device__ __forceinline__ float wave_min(float v){
  #pragma unroll
  for(int o=32;o;o>>=1) v = fminf(v,__shfl_xor(v,o));
  return v;
}
__device__ __forceinline__ float blk_sum256(float v){
  __shared__ float sm[4];
  v = wave_sum(v);
  __syncthreads();
  if((threadIdx.x&63)==0) sm[threadIdx.x>>6]=v;
  __syncthreads();
  return sm[0]+sm[1]+sm[2]+sm[3];
}
__device__ __forceinline__ float blk_min256(float v){
  __shared__ float sm[4];
  v = wave_min(v);
  __syncthreads();
  if((threadIdx.x&63)==0) sm[threadIdx.x>>6]=v;
  __syncthreads();
  return fminf(fminf(sm[0],sm[1]),fminf(sm[2],sm[3]));
}
__device__ __forceinline__ float blk_max256(float v){
  __shared__ float sm[4];
  v = wave_max(v);
  __syncthreads();
  if((threadIdx.x&63)==0) sm[threadIdx.x>>6]=v;
  __syncthreads();
  return fmaxf(fmaxf(sm[0],sm[1]),fmaxf(sm[2],sm[3]));
}

// ---------------- GEMM: C[M,Nc] = A[M,K](bf16,rm) @ Bt[Nc,K](bf16,rm)^T ----
// 3-buffer deep pipeline: counted vmcnt(8) keeps 2 K-tiles in flight ACROSS
// raw s_barriers (T4). Barrier #2 after lgkmcnt(0) protects buffer reuse.
// XOR source-pre-swizzle (both sides) halves LDS read conflicts.
// LDS-bounce epilogue -> coalesced 128B-line stores.
// Split-K over gridDim.z into bf16 planes; XCD-chunked tile swizzle.
// MODE 0: write bf16 plane z.  MODE 1: write bf16 Cb + global min/max atomics.

template<int VW> __device__ __forceinline__ void waitv(){
  if constexpr(VW==8) asm volatile("s_waitcnt vmcnt(8)" ::: "memory");
  else if constexpr(VW==4) asm volatile("s_waitcnt vmcnt(4)" ::: "memory");
  else asm volatile("s_waitcnt vmcnt(0)" ::: "memory");
}

#define STG4(bb,k0) do{ \
  __builtin_amdgcn_global_load_lds((__attribute__((address_space(1))) void*)(gA0+(k0)), (__attribute__((address_space(3))) void*)(lds + (bb)*4096 + (wid<<9)),        16, 0, 0); \
  __builtin_amdgcn_global_load_lds((__attribute__((address_space(1))) void*)(gA1+(k0)), (__attribute__((address_space(3))) void*)(lds + (bb)*4096 + 2048 + (wid<<9)), 16, 0, 0); \
  __builtin_amdgcn_global_load_lds((__attribute__((address_space(1))) void*)(gB0+(k0)), (__attribute__((address_space(3))) void*)(lds + 12288 + (bb)*4096 + (wid<<9)),        16, 0, 0); \
  __builtin_amdgcn_global_load_lds((__attribute__((address_space(1))) void*)(gB1+(k0)), (__attribute__((address_space(3))) void*)(lds + 12288 + (bb)*4096 + 2048 + (wid<<9)), 16, 0, 0); \
}while(0)

template<int MODE>
__global__ __launch_bounds__(256) void gemm_bt(
  const u16* __restrict__ A, const u16* __restrict__ Bt,
  int M, int Nc, int K,
  u16* __restrict__ Cb, unsigned* __restrict__ mmx)
{
  __shared__ __align__(16) u16 lds[3*4096*2];   // 48 KB: 3x(A 8KB + B 8KB)
  const int tid = threadIdx.x;
  const int wid = tid>>6, lane = tid&63;

  // XCD-chunked swizzle of the (x,y) tile space within this z-slice.
  const int gx = gridDim.x;
  int lid = blockIdx.y*gx + blockIdx.x;
  const int nwg = gx*gridDim.y;
  if ((nwg & 7) == 0) {
    const int chunk = nwg >> 3;
    lid = (lid & 7)*chunk + (lid >> 3);
  }
  const int m0 = (lid/gx)<<7, n0 = (lid%gx)<<7;
  const int wr = wid>>1, wc = wid&1;

  const int Klen = K / gridDim.z;
  const int kbeg = blockIdx.z * Klen;

  // staging: per wave 64 lanes x 16B = 16 rows of 64B, LDS-linear in lane.
  // Global column chunk is XOR-swizzled by row (involution with read side).
  const int srow = (wid<<4) + (lane>>2);                 // 0..63
  const int scol = (((lane&3) ^ ((lane>>2)&3))<<3);      // swizzled 8-elem chunk
  const u16* gA0 = A  + (size_t)(m0+srow   )*K + scol;
  const u16* gA1 = A  + (size_t)(m0+srow+64)*K + scol;
  const u16* gB0 = Bt + (size_t)(n0+srow   )*K + scol;
  const u16* gB1 = Bt + (size_t)(n0+srow+64)*K + scol;

  f32x4 acc[4][4] = {};
  const int lr = lane&15, lk = (lane>>4)<<3;
  const int rdo = lk ^ ((lr&3)<<3);                      // swizzled read offset

  const int NIT = Klen>>5;
  // prologue: stage 3 tiles (NIT >= 3 for all launches in this pipeline)
  STG4(0, kbeg);
  STG4(1, kbeg+32);
  STG4(2, kbeg+64);

  for (int it=0; it<NIT-2; ++it){
    const int b = it - (it/3)*3;
    waitv<8>();                          // tile it staged (2 tiles stay in flight)
    __builtin_amdgcn_s_barrier();        // all waves' tile-it staging done
    const u16* baseA = lds + b*4096;
    const u16* baseB = lds + 12288 + b*4096;
    s16x8 af[4], bfr[4];
    #pragma unroll
    for(int m=0;m<4;m++) af[m]  = *(const s16x8*)(baseA + ((wr<<6)+(m<<4)+lr)*32 + rdo);
    #pragma unroll
    for(int n=0;n<4;n++) bfr[n] = *(const s16x8*)(baseB + ((wc<<6)+(n<<4)+lr)*32 + rdo);
    asm volatile("s_waitcnt lgkmcnt(0)" ::: "memory");   // reads retired
    __builtin_amdgcn_sched_barrier(0);
    __builtin_amdgcn_s_barrier();        // all waves done reading buf b
    if (it+3 < NIT) STG4(b, kbeg + ((it+3)<<5));         // overwrite buf b
    #pragma unroll
    for(int m=0;m<4;m++)
      #pragma unroll
      for(int n=0;n<4;n++)
        acc[m][n] = __builtin_amdgcn_mfma_f32_16x16x32_bf16(af[m], bfr[n], acc[m][n], 0,0,0);
  }
  // peeled tail (no more staging; buffers never reused again)
  {
    const int it = NIT-2; const int b = it - (it/3)*3;
    waitv<4>();
    __builtin_amdgcn_s_barrier();
    const u16* baseA = lds + b*4096;
    const u16* baseB = lds + 12288 + b*4096;
    s16x8 af[4], bfr[4];
    #pragma unroll
    for(int m=0;m<4;m++) af[m]  = *(const s16x8*)(baseA + ((wr<<6)+(m<<4)+lr)*32 + rdo);
    #pragma unroll
    for(int n=0;n<4;n++) bfr[n] = *(const s16x8*)(baseB + ((wc<<6)+(n<<4)+lr)*32 + rdo);
    #pragma unroll
    for(int m=0;m<4;m++)
      #pragma unroll
      for(int n=0;n<4;n++)
        acc[m][n] = __builtin_amdgcn_mfma_f32_16x16x32_bf16(af[m], bfr[n], acc[m][n], 0,0,0);
  }
  {
    const int it = NIT-1; const int b = it - (it/3)*3;
    waitv<0>();
    __builtin_amdgcn_s_barrier();
    const u16* baseA = lds + b*4096;
    const u16* baseB = lds + 12288 + b*4096;
    s16x8 af[4], bfr[4];
    #pragma unroll
    for(int m=0;m<4;m++) af[m]  = *(const s16x8*)(baseA + ((wr<<6)+(m<<4)+lr)*32 + rdo);
    #pragma unroll
    for(int n=0;n<4;n++) bfr[n] = *(const s16x8*)(baseB + ((wc<<6)+(n<<4)+lr)*32 + rdo);
    #pragma unroll
    for(int m=0;m<4;m++)
      #pragma unroll
      for(int n=0;n<4;n++)
        acc[m][n] = __builtin_amdgcn_mfma_f32_16x16x32_bf16(af[m], bfr[n], acc[m][n], 0,0,0);
  }

  // MODE 1: min/max from registers (before LDS reuse)
  float tmin = 3.0e38f, tmax = -3.0e38f;
  if (MODE==1){
    #pragma unroll
    for(int m=0;m<4;m++)
      #pragma unroll
      for(int n=0;n<4;n++){
        f32x4 v = acc[m][n];
        #pragma unroll
        for(int e=0;e<4;e++){ tmin = fminf(tmin,v[e]); tmax = fmaxf(tmax,v[e]); }
      }
  }

  // ---- epilogue: bounce through LDS for coalesced 128B-line stores ----
  __syncthreads();                       // k-loop LDS dead
  u16* lC = lds;                         // 128x128 u16 = 32 KB
  {
    const int rb_l = (wr<<6) + ((lane>>4)<<2);
    const int cb_l = (wc<<6) + lr;
    #pragma unroll
    for(int m=0;m<4;m++)
      #pragma unroll
      for(int n=0;n<4;n++){
        f32x4 v = acc[m][n];
        #pragma unroll
        for(int e=0;e<4;e++)
          lC[(rb_l+(m<<4)+e)*128 + cb_l+(n<<4)] = f2b(v[e]);
      }
  }
  __syncthreads();
  u16* Cp = (MODE==0) ? (Cb + (size_t)blockIdx.z * M * Nc) : Cb;
  #pragma unroll
  for(int q=0;q<8;q++){
    int c = (q<<8) + tid;                // 16B chunk index in 128x128 tile
    int r = c>>4, cc = (c&15)<<3;
    *(s16x8*)(Cp + (size_t)(m0+r)*Nc + n0 + cc) = *(const s16x8*)(lC + r*128 + cc);
  }

  if (MODE==1){
    tmin = wave_min(tmin); tmax = wave_max(tmax);
    __shared__ float rmn[4], rmx[4];
    if(lane==0){ rmn[wid]=tmin; rmx[wid]=tmax; }
    __syncthreads();
    if(tid==0){
      float mn=fminf(fminf(rmn[0],rmn[1]),fminf(rmn[2],rmn[3]));
      float mx=fmaxf(fmaxf(rmx[0],rmx[1]),fmaxf(rmx[2],rmx[3]));
      atomicMin(mmx+0, fkey(mn));
      atomicMax(mmx+1, fkey(mx));
    }
  }
}

// src [R][C] fp32 -> dst [C][R] bf16   (weight prep)
__global__ __launch_bounds__(256) void transpose_cast(
  const float* __restrict__ src, u16* __restrict__ dst, int R, int C)
{
  __shared__ float t[32][33];
  int c0 = blockIdx.x<<5, r0 = blockIdx.y<<5;
  int tx = threadIdx.x&31, ty = threadIdx.x>>5;
  #pragma unroll
  for(int i=0;i<32;i+=8) t[ty+i][tx] = src[(size_t)(r0+ty+i)*C + c0+tx];
  __syncthreads();
  #pragma unroll
  for(int i=0;i<32;i+=8) dst[(size_t)(c0+ty+i)*R + r0+tx] = f2b(t[tx][ty+i]);
}

// dst[C][R] bf16 = transpose( sum_p bf16_plane_p [R][C] )
__global__ __launch_bounds__(256) void transpose_sum_bf(
  const u16* __restrict__ src, size_t pstr, int nsp,
  u16* __restrict__ dst, int R, int C)
{
  __shared__ float t[32][33];
  int c0 = blockIdx.x<<5, r0 = blockIdx.y<<5;
  int tx = threadIdx.x&31, ty = threadIdx.x>>5;
  #pragma unroll
  for(int i=0;i<32;i+=8){
    float v = 0;
    for(int p=0;p<nsp;p++)
      v += b2f(src[(size_t)p*pstr + (size_t)(r0+ty+i)*C + c0+tx]);
    t[ty+i][tx] = v;
  }
  __syncthreads();
  #pragma unroll
  for(int i=0;i<32;i+=8) dst[(size_t)(c0+ty+i)*R + r0+tx] = f2b(t[tx][ty+i]);
}

__global__ __launch_bounds__(256) void prep_x(const float* __restrict__ x,
  u16* __restrict__ xb, u16* __restrict__ xnb)
{
  int row = blockIdx.x, t = threadIdx.x;
  const float* p = x + (size_t)row*L_ + (t<<2);
  f32x4 v = *(const f32x4*)p;
  float ss = v[0]*v[0]+v[1]*v[1]+v[2]*v[2]+v[3]*v[3];
  float tot = blk_sum256(ss);
  float inv = 1.0f/fmaxf(sqrtf(tot), 1e-12f);
  u16* pb = xb  + (size_t)row*L_ + (t<<2);
  u16* pn = xnb + (size_t)row*L_ + (t<<2);
  #pragma unroll
  for(int k=0;k<4;k++){ pb[k]=f2b(v[k]); pn[k]=f2b(v[k]*inv); }
}

__global__ __launch_bounds__(256) void attn_epi(const u16* __restrict__ A1, const u16* __restrict__ B1,
  size_t pstr, int nsp,
  const float* __restrict__ ba, const float* __restrict__ bb,
  const float* __restrict__ wc, const float* __restrict__ bc,
  float* __restrict__ agg, float* __restrict__ s)
{
  int row = (blockIdx.x<<2) + (threadIdx.x>>6);
  int lane = threadIdx.x&63;
  float a[4]={0,0,0,0}, b[4]={0,0,0,0};
  for(int p=0;p<nsp;p++){
    s16x4 ua = *(const s16x4*)(A1 + (size_t)p*pstr + (size_t)row*H_ + (lane<<2));
    s16x4 ub = *(const s16x4*)(B1 + (size_t)p*pstr + (size_t)row*H_ + (lane<<2));
    #pragma unroll
    for(int j=0;j<4;j++){ a[j]+=b2f((u16)ua[j]); b[j]+=b2f((u16)ub[j]); }
  }
  float acc=0;
  #pragma unroll
  for(int j=0;j<4;j++){
    int h = (lane<<2)+j;
    float tv = tanhf(a[j]+ba[h]);
    float sg = 1.0f/(1.0f+expf(-(b[j]+bb[h])));
    acc += tv*sg*wc[h];
  }
  acc = wave_sum(acc);
  if(lane==0){
    float v = acc + bc[0];
    agg[row]=v;
    s[row]=1.0f/(1.0f+expf(-v));
  }
}

__global__ __launch_bounds__(256) void s_stats(const float* __restrict__ s, float* __restrict__ sc){
  int t=threadIdx.x;
  float sum=0, mn=3e38f, mx=-3e38f;
  for(int i=t;i<N_;i+=256){ float v=s[i]; sum+=v; mn=fminf(mn,v); mx=fmaxf(mx,v); }
  float S=blk_sum256(sum);
  float MN=blk_min256(mn);
  float MX=blk_max256(mx);
  if(t==0){ sc[0]=S; sc[1]=MN; sc[2]=MX; }
}

// awb[i][j] = bf16( (c1 + beta*s_i*s_j + maps_ij) / rowsum_i ) — single pass,
// maps row held in registers (24 per thread).
__global__ __launch_bounds__(256) void aw_write(const float* __restrict__ maps, const float* __restrict__ s,
  const float* __restrict__ sc, u16* __restrict__ awb)
{
  int i = blockIdx.x, t = threadIdx.x;
  float smin = sc[1], smax = sc[2];
  float mn = smin*smin, mx = smax*smax;
  float beta = 0.6f/(mx-mn);
  float c1 = 0.4f - beta*mn;
  float si = s[i];
  const float* mrow = maps + (size_t)i*N_;
  float mv[24];
  float part = 0;
  #pragma unroll
  for(int q=0;q<24;q++){
    int j = t + (q<<8);
    mv[q] = c1 + beta*si*s[j] + mrow[j];
    part += mv[q];
  }
  float r = blk_sum256(part);
  float inv = 1.0f/fmaxf(r, 1e-12f);
  u16* orow = awb + (size_t)i*N_;
  #pragma unroll
  for(int q=0;q<24;q++) orow[t + (q<<8)] = f2b(mv[q]*inv);
}

// out = relu(LN( (sum_p Y_p)*rowscale + bias; g, bn)); planes are bf16
__global__ __launch_bounds__(256) void ln_epi512(const u16* __restrict__ Y, size_t pstr, int nsp,
  const float* __restrict__ ki,
  const float* __restrict__ bias, const float* __restrict__ g, const float* __restrict__ bn,
  u16* __restrict__ outb)
{
  int row = (blockIdx.x<<2)+(threadIdx.x>>6);
  int lane = threadIdx.x&63;
  int c0 = lane<<3;
  float v[8] = {0,0,0,0,0,0,0,0};
  for(int p=0;p<nsp;p++){
    s16x8 u = *(const s16x8*)(Y + (size_t)p*pstr + (size_t)row*D_ + c0);
    #pragma unroll
    for(int j=0;j<8;j++) v[j] += b2f((u16)u[j]);
  }
  float scale = ki ? (1.0f/ki[row]) : 1.0f;
  float sum=0, ssum=0;
  #pragma unroll
  for(int j=0;j<8;j++){ v[j] = v[j]*scale + bias[c0+j]; sum+=v[j]; ssum+=v[j]*v[j]; }
  sum = wave_sum(sum); ssum = wave_sum(ssum);
  float m = sum*(1.0f/D_);
  float var = ssum*(1.0f/D_) - m*m;
  float invsd = rsqrtf(var + 1e-5f);
  u16 ob[8];
  #pragma unroll
  for(int j=0;j<8;j++){
    float o = (v[j]-m)*invsd*g[c0+j] + bn[c0+j];
    o = fmaxf(o, 0.0f);
    ob[j] = f2b(o);
  }
  *(s16x8*)(outb + (size_t)row*D_ + c0) = *(s16x8*)ob;
}

__global__ __launch_bounds__(256) void bias_cast(const u16* __restrict__ Y, size_t pstr, int nsp,
  const float* __restrict__ b, u16* __restrict__ outb)
{
  size_t idx = ((size_t)blockIdx.x*256 + threadIdx.x)<<3;
  float v[8] = {0,0,0,0,0,0,0,0};
  for(int p=0;p<nsp;p++){
    s16x8 u = *(const s16x8*)(Y + (size_t)p*pstr + idx);
    #pragma unroll
    for(int j=0;j<8;j++) v[j] += b2f((u16)u[j]);
  }
  int c = (int)(idx & (D_-1));
  u16 ob[8];
  #pragma unroll
  for(int k=0;k<8;k++) ob[k] = f2b(v[k]+b[c+k]);
  *(s16x8*)(outb+idx) = *(s16x8*)ob;
}

__global__ void init_k(unsigned* mmx){ mmx[0]=0xFFFFFFFFu; mmx[1]=0u; }

// binarize in place + row count + fused trans/z epilogue (saves a full BIG pass)
__global__ __launch_bounds__(256) void binarize(u16* __restrict__ csb,
  const unsigned* __restrict__ mmx, const float* __restrict__ agg,
  float* __restrict__ ki, float* __restrict__ z)
{
  int i = blockIdx.x, t = threadIdx.x;
  float mn = funkey(mmx[0]), mx = funkey(mmx[1]);
  float th = mn + 0.5f*(mx-mn);
  u16* row = csb + (size_t)i*N_;
  float cnt = 0, dot = 0;
  #pragma unroll
  for(int q=0;q<24;q++){
    int j = t + (q<<8);
    bool on = b2f(row[j]) >= th;
    row[j] = on ? (u16)0x3F80 : (u16)0;
    if(on){ cnt += 1.0f; dot += agg[j]; }
  }
  float k = blk_sum256(cnt);
  float dt = blk_sum256(dot);
  if(t==0){
    ki[i] = k;
    float tr = dt/(k*sqrtf((float)N_));
    z[i] = 0.3f*tr + 0.7f*agg[i];
  }
}

__global__ __launch_bounds__(1024) void softmax_prep(const float* __restrict__ z,
  float* __restrict__ e, float* __restrict__ sexp)
{
  int t = threadIdx.x;
  __shared__ float sm[16];
  float mx=-3e38f;
  for(int i=t;i<N_;i+=1024) mx=fmaxf(mx,z[i]);
  mx = wave_max(mx);
  if((t&63)==0) sm[t>>6]=mx;
  __syncthreads();
  float zm = sm[0];
  #pragma unroll
  for(int w=1;w<16;w++) zm=fmaxf(zm,sm[w]);
  __syncthreads();
  float sum=0;
  for(int i=t;i<N_;i+=1024){ float ee=expf(z[i]-zm); e[i]=ee; sum+=ee; }
  sum = wave_sum(sum);
  if((t&63)==0) sm[t>>6]=sum;
  __syncthreads();
  if(t==0){ float S=0; for(int w=0;w<16;w++) S+=sm[w]; *sexp=S; }
}

// pooled partial sums; g2/g1 are bf16 [N,512]
__global__ __launch_bounds__(256) void pooled_partial(const float* __restrict__ e,
  const u16* __restrict__ g2b, const u16* __restrict__ g1b, float* __restrict__ part)
{
  int b = blockIdx.x, t = threadIdx.x;
  float a0=0,a1=0,a2=0,a3=0;
  for(int r=0;r<24;r++){
    int row = b*24+r;
    float w = e[row];
    a0 += w * b2f(g2b[(size_t)row*D_ + t]);
    a1 += w * b2f(g2b[(size_t)row*D_ + t+256]);
    a2 += w * b2f(g1b[(size_t)row*D_ + t]);
    a3 += w * b2f(g1b[(size_t)row*D_ + t+256]);
  }
  part[(size_t)b*1024 + t]      = a0;
  part[(size_t)b*1024 + t+256]  = a1;
  part[(size_t)b*1024 + t+512]  = a2;
  part[(size_t)b*1024 + t+768]  = a3;
}

__global__ __launch_bounds__(1024) void final_k(const float* __restrict__ part, const float* __restrict__ sexp,
  const float* __restrict__ lng, const float* __restrict__ lnb,
  const float* __restrict__ clsw, float* __restrict__ out)
{
  int t = threadIdx.x;
  __shared__ float red[16];
  __shared__ float smv[1024];
  __shared__ float lgs[4];
  float p=0;
  for(int b=0;b<256;b++) p += part[b*1024 + t];
  p /= sexp[0];
  float w = wave_sum(p);
  if((t&63)==0) red[t>>6]=w;
  __syncthreads();
  float tot=0;
  #pragma unroll
  for(int i2=0;i2<16;i2++) tot+=red[i2];
  float m = tot*(1.0f/1024.0f);
  __syncthreads();
  float d = p-m;
  w = wave_sum(d*d);
  if((t&63)==0) red[t>>6]=w;
  __syncthreads();
  tot=0;
  #pragma unroll
  for(int i2=0;i2<16;i2++) tot+=red[i2];
  float var = tot*(1.0f/1024.0f);
  float y = d*rsqrtf(var+1e-5f)*lng[t] + lnb[t];
  smv[t]=y;
  __syncthreads();
  if(t<4){
    float lg=0;
    for(int j=0;j<1024;j++) lg += smv[j]*clsw[j*4+t];
    lgs[t]=lg;
  }
  __syncthreads();
  if(t==0){
    float h[4];
    int am=0; float best=lgs[0];
    #pragma unroll
    for(int c2=0;c2<4;c2++){ h[c2]=1.0f/(1.0f+expf(-lgs[c2])); if(lgs[c2]>best){best=lgs[c2];am=c2;} }
    float sv=1.0f;
    #pragma unroll
    for(int c2=0;c2<4;c2++){ out[c2]=h[c2]; sv*=(1.0f-h[c2]); out[4+c2]=sv; }
    out[8]=(float)am;
  }
}

extern "C" void kernel_launch(void* const* d_in, const int* in_sizes, int n_in,
                              void* d_out, int out_size, void* d_ws, size_t ws_size,
                              hipStream_t stream)
{
  const float* x_path =(const float*)d_in[0];
  const float* maps   =(const float*)d_in[1];
  const float* nl0_w1 =(const float*)d_in[2];
  const float* nl0_b1 =(const float*)d_in[3];
  const float* nl0_g  =(const float*)d_in[4];
  const float* nl0_bn =(const float*)d_in[5];
  const float* nl0_w2 =(const float*)d_in[6];
  const float* nl0_b2 =(const float*)d_in[7];
  const float* nl1_w1 =(const float*)d_in[8];
  const float* nl1_b1 =(const float*)d_in[9];
  const float* nl1_g  =(const float*)d_in[10];
  const float* nl1_bn =(const float*)d_in[11];
  const float* nl1_w2 =(const float*)d_in[12];
  const float* nl1_b2 =(const float*)d_in[13];
  const float *gw[6], *gb[6], *gg[6], *gbn[6];   // gc0,gc1,gc2,ga0,ga1,ga2
  for(int l=0;l<6;l++){
    gw[l]  = (const float*)d_in[14+l*4+0];
    gb[l]  = (const float*)d_in[14+l*4+1];
    gg[l]  = (const float*)d_in[14+l*4+2];
    gbn[l] = (const float*)d_in[14+l*4+3];
  }
  const float* attn_wa=(const float*)d_in[38];
  const float* attn_ba=(const float*)d_in[39];
  const float* attn_wb=(const float*)d_in[40];
  const float* attn_bb=(const float*)d_in[41];
  const float* attn_wc=(const float*)d_in[42];
  const float* attn_bc=(const float*)d_in[43];
  const float* cls_w  =(const float*)d_in[44];
  const float* ln_g   =(const float*)d_in[45];
  const float* ln_b   =(const float*)d_in[46];

  char* ws=(char*)d_ws;
  size_t off=0;
  auto alc=[&](size_t b)->char*{ char* p=ws+off; off=(off+b+255)&~(size_t)255; return p; };
  u16* BIG = (u16*)alc((size_t)N_*N_*2);         // awb, then cs/binary (time-shared)
  u16* XB  = (u16*)alc((size_t)N_*L_*2);
  u16* XNB = (u16*)alc((size_t)N_*L_*2);
  u16* WT_nl0w1=(u16*)alc((size_t)D_*L_*2);
  u16* WT_nl0w2=(u16*)alc((size_t)D_*D_*2);
  u16* WT_nl1w1=(u16*)alc((size_t)D_*L_*2);
  u16* WT_nl1w2=(u16*)alc((size_t)D_*D_*2);
  u16* WT_g[6];
  for(int l=0;l<6;l++) WT_g[l]=(u16*)alc((size_t)D_*D_*2);
  u16* WT_wa=(u16*)alc((size_t)H_*L_*2);
  u16* WT_wb=(u16*)alc((size_t)H_*L_*2);
  const int SK = 4;                               // split-K factor
  u16* SP = (u16*)alc((size_t)SK*N_*D_*2);        // split-K bf16 planes
  u16* XWT=(u16*)alc((size_t)D_*N_*2);
  u16* XA =(u16*)alc((size_t)N_*D_*2);
  u16* XBv=(u16*)alc((size_t)N_*D_*2);
  u16* X0B=(u16*)alc((size_t)N_*D_*2);
  u16* X1B=(u16*)alc((size_t)N_*D_*2);
  float* PART=(float*)alc((size_t)256*1024*4);
  float* AGG=(float*)alc(N_*4);
  float* SS =(float*)alc(N_*4);
  float* KI =(float*)alc(N_*4);
  float* Z  =(float*)alc(N_*4);
  float* E  =(float*)alc(N_*4);
  float* SC =(float*)alc(256);
  unsigned* MMX=(unsigned*)alc(256);
  float* SEXP=(float*)alc(256);

  const size_t PS_D = (size_t)N_*D_;
  const size_t PS_H = (size_t)N_*H_;
  u16* A1 = SP;                      // SK planes of [N,H]
  u16* B1 = SP + (size_t)SK*PS_H;    // SK planes of [N,H]

  init_k<<<1,1,0,stream>>>(MMX);
  prep_x<<<N_,256,0,stream>>>(x_path, XB, XNB);

  transpose_cast<<<dim3(D_/32, L_/32),256,0,stream>>>(nl0_w1, WT_nl0w1, L_, D_);
  transpose_cast<<<dim3(D_/32, D_/32),256,0,stream>>>(nl0_w2, WT_nl0w2, D_, D_);
  transpose_cast<<<dim3(D_/32, L_/32),256,0,stream>>>(nl1_w1, WT_nl1w1, L_, D_);
  transpose_cast<<<dim3(D_/32, D_/32),256,0,stream>>>(nl1_w2, WT_nl1w2, D_, D_);
  for(int l=0;l<6;l++)
    transpose_cast<<<dim3(D_/32, D_/32),256,0,stream>>>(gw[l], WT_g[l], D_, D_);
  transpose_cast<<<dim3(H_/32, L_/32),256,0,stream>>>(attn_wa, WT_wa, L_, H_);
  transpose_cast<<<dim3(H_/32, L_/32),256,0,stream>>>(attn_wb, WT_wb, L_, H_);

  // gated attention -> agg, s
  gemm_bt<0><<<dim3(H_/128, N_/128, SK),256,0,stream>>>(XB, WT_wa, N_, H_, L_, A1, nullptr);
  gemm_bt<0><<<dim3(H_/128, N_/128, SK),256,0,stream>>>(XB, WT_wb, N_, H_, L_, B1, nullptr);
  attn_epi<<<N_/4,256,0,stream>>>(A1,B1,PS_H,SK,attn_ba,attn_bb,attn_wc,attn_bc,AGG,SS);
  s_stats<<<1,256,0,stream>>>(SS,SC);

  // aw adjacency (l1-normalized, bf16) into BIG
  aw_write<<<N_,256,0,stream>>>(maps,SS,SC,BIG);

  // x1 = nonlin(x; nl1)
  gemm_bt<0><<<dim3(D_/128,N_/128,SK),256,0,stream>>>(XB, WT_nl1w1, N_,D_,L_, SP, nullptr);
  ln_epi512<<<N_/4,256,0,stream>>>(SP,PS_D,SK,nullptr,nl1_b1,nl1_g,nl1_bn,XA);
  gemm_bt<0><<<dim3(D_/128,N_/128,SK),256,0,stream>>>(XA, WT_nl1w2, N_,D_,D_, SP, nullptr);
  bias_cast<<<(N_*D_/8)/256,256,0,stream>>>(SP,PS_D,SK, nl1_b2, X1B);

  // ga chain (adjacency = BIG = awb, already row-normalized)
  {
    const u16* cur=X1B;
    for(int l=0;l<3;l++){
      int gi = 3+l; // ga0..ga2
      gemm_bt<0><<<dim3(D_/128,N_/128,SK),256,0,stream>>>(cur, WT_g[gi], N_,D_,D_, SP, nullptr);
      transpose_sum_bf<<<dim3(D_/32, N_/32),256,0,stream>>>(SP, PS_D, SK, XWT, N_, D_);
      gemm_bt<0><<<dim3(D_/128,N_/128,SK),256,0,stream>>>(BIG, XWT, N_,D_,N_, SP, nullptr);
      u16* nxt = (l==0)? XA : (l==1)? XBv : X1B;
      ln_epi512<<<N_/4,256,0,stream>>>(SP,PS_D,SK, nullptr, gb[gi], gg[gi], gbn[gi], nxt);
      cur = nxt;
    }
  }

  // x0 = nonlin(x; nl0)
  gemm_bt<0><<<dim3(D_/128,N_/128,SK),256,0,stream>>>(XB, WT_nl0w1, N_,D_,L_, SP, nullptr);
  ln_epi512<<<N_/4,256,0,stream>>>(SP,PS_D,SK,nullptr,nl0_b1,nl0_g,nl0_bn,XA);
  gemm_bt<0><<<dim3(D_/128,N_/128,SK),256,0,stream>>>(XA, WT_nl0w2, N_,D_,D_, SP, nullptr);
  bias_cast<<<(N_*D_/8)/256,256,0,stream>>>(SP,PS_D,SK, nl0_b2, X0B);

  // cosine gram -> BIG (bf16) + global min/max; then binarize (+fused trans/z)
  gemm_bt<1><<<dim3(N_/128,N_/128,1),256,0,stream>>>(XNB, XNB, N_,N_,L_, BIG, MMX);
  binarize<<<N_,256,0,stream>>>(BIG, MMX, AGG, KI, Z);

  // gc chain (adjacency = BIG binary, rowscale = 1/ki)
  {
    const u16* cur=X0B;
    for(int l=0;l<3;l++){
      int gi = l; // gc0..gc2
      gemm_bt<0><<<dim3(D_/128,N_/128,SK),256,0,stream>>>(cur, WT_g[gi], N_,D_,D_, SP, nullptr);
      transpose_sum_bf<<<dim3(D_/32, N_/32),256,0,stream>>>(SP, PS_D, SK, XWT, N_, D_);
      gemm_bt<0><<<dim3(D_/128,N_/128,SK),256,0,stream>>>(BIG, XWT, N_,D_,N_, SP, nullptr);
      u16* nxt = (l==0)? XA : (l==1)? XBv : X0B;
      ln_epi512<<<N_/4,256,0,stream>>>(SP,PS_D,SK, KI, gb[gi], gg[gi], gbn[gi], nxt);
      cur = nxt;
    }
  }

  // pooling + head
  softmax_prep<<<1,1024,0,stream>>>(Z,E,SEXP);
  pooled_partial<<<256,256,0,stream>>>(E,X1B,X0B,PART);
  final_k<<<1,1024,0,stream>>>(PART,SEXP,ln_g,ln_b,cls_w,(float*)d_out);

  (void)in_sizes;(void)n_in;(void)out_size;(void)ws_size;
}

// Round 5
// 869.728 us; speedup vs baseline: 1.7635x; 1.0519x over previous
//
#include <hip/hip_runtime.h>

#define N_ 6144
#define L_ 1024
#define D_ 512
#define H_ 256
#define SPARSE_MAX 64u

typedef unsigned short u16;
typedef unsigned long long u64;
typedef __attribute__((ext_vector_type(4))) float f32x4;
typedef __attribute__((ext_vector_type(8))) short s16x8;
typedef __attribute__((ext_vector_type(4))) short s16x4;

__device__ __forceinline__ u16 f2b(float f){
  unsigned u = __float_as_uint(f);
  u += 0x7FFFu + ((u >> 16) & 1u);
  return (u16)(u >> 16);
}
__device__ __forceinline__ float b2f(u16 h){ return __uint_as_float(((unsigned)h) << 16); }
__device__ __forceinline__ unsigned fkey(float f){
  unsigned u = __float_as_uint(f);
  return (u & 0x80000000u) ? ~u : (u | 0x80000000u);
}
__device__ __forceinline__ float funkey(unsigned k){
  unsigned u = (k & 0x80000000u) ? (k & 0x7FFFFFFFu) : ~k;
  return __uint_as_float(u);
}
__device__ __forceinline__ float wave_sum(float v){
  #pragma unroll
  for(int o=32;o;o>>=1) v += __shfl_xor(v,o);
  return v;
}
__device__ __forceinline__ float wave_max(float v){
  #pragma unroll
  for(int o=32;o;o>>=1) v = fmaxf(v,__shfl_xor(v,o));
  return v;
}
__device__ __forceinline__ float wave_min(float v){
  #pragma unroll
  for(int o=32;o;o>>=1) v = fminf(v,__shfl_xor(v,o));
  return v;
}
__device__ __forceinline__ float blk_sum256(float v){
  __shared__ float sm[4];
  v = wave_sum(v);
  __syncthreads();
  if((threadIdx.x&63)==0) sm[threadIdx.x>>6]=v;
  __syncthreads();
  return sm[0]+sm[1]+sm[2]+sm[3];
}
__device__ __forceinline__ float blk_min256(float v){
  __shared__ float sm[4];
  v = wave_min(v);
  __syncthreads();
  if((threadIdx.x&63)==0) sm[threadIdx.x>>6]=v;
  __syncthreads();
  return fminf(fminf(sm[0],sm[1]),fminf(sm[2],sm[3]));
}
__device__ __forceinline__ float blk_max256(float v){
  __shared__ float sm[4];
  v = wave_max(v);
  __syncthreads();
  if((threadIdx.x&63)==0) sm[threadIdx.x>>6]=v;
  __syncthreads();
  return fmaxf(fmaxf(sm[0],sm[1]),fmaxf(sm[2],sm[3]));
}

// ---------------- GEMM: C[M,Nc] = A[M,K](bf16,rm) @ Bt[Nc,K](bf16,rm)^T ----
// 3-buffer pipeline w/ counted vmcnt; XOR-swizzled LDS; LDS-bounce epilogue.
// Split-K over gridDim.z into bf16 planes. gate!=null && gate[2]<=SPARSE_MAX
// -> early exit (sparse path handles this product).
// MODE 0: write bf16 plane z.  MODE 1: NT-write bf16 Cb + min/max atomics.

template<int VW> __device__ __forceinline__ void waitv(){
  if constexpr(VW==8) asm volatile("s_waitcnt vmcnt(8)" ::: "memory");
  else if constexpr(VW==4) asm volatile("s_waitcnt vmcnt(4)" ::: "memory");
  else asm volatile("s_waitcnt vmcnt(0)" ::: "memory");
}

#define STG4(bb,k0) do{ \
  __builtin_amdgcn_global_load_lds((__attribute__((address_space(1))) void*)(gA0+(k0)), (__attribute__((address_space(3))) void*)(lds + (bb)*4096 + (wid<<9)),        16, 0, 0); \
  __builtin_amdgcn_global_load_lds((__attribute__((address_space(1))) void*)(gA1+(k0)), (__attribute__((address_space(3))) void*)(lds + (bb)*4096 + 2048 + (wid<<9)), 16, 0, 0); \
  __builtin_amdgcn_global_load_lds((__attribute__((address_space(1))) void*)(gB0+(k0)), (__attribute__((address_space(3))) void*)(lds + 12288 + (bb)*4096 + (wid<<9)),        16, 0, 0); \
  __builtin_amdgcn_global_load_lds((__attribute__((address_space(1))) void*)(gB1+(k0)), (__attribute__((address_space(3))) void*)(lds + 12288 + (bb)*4096 + 2048 + (wid<<9)), 16, 0, 0); \
}while(0)

template<int MODE>
__global__ __launch_bounds__(256) void gemm_bt(
  const u16* __restrict__ A, const u16* __restrict__ Bt,
  int M, int Nc, int K,
  u16* __restrict__ Cb, unsigned* __restrict__ mmx,
  const unsigned* __restrict__ gate)
{
  if (gate && gate[2] <= SPARSE_MAX) return;
  __shared__ __align__(16) u16 lds[3*4096*2];   // 48 KB
  const int tid = threadIdx.x;
  const int wid = tid>>6, lane = tid&63;

  const int gx = gridDim.x;
  int lid = blockIdx.y*gx + blockIdx.x;
  const int nwg = gx*gridDim.y;
  if ((nwg & 7) == 0) {
    const int chunk = nwg >> 3;
    lid = (lid & 7)*chunk + (lid >> 3);
  }
  const int m0 = (lid/gx)<<7, n0 = (lid%gx)<<7;
  const int wr = wid>>1, wc = wid&1;

  const int Klen = K / gridDim.z;
  const int kbeg = blockIdx.z * Klen;

  const int srow = (wid<<4) + (lane>>2);
  const int scol = (((lane&3) ^ ((lane>>2)&3))<<3);
  const u16* gA0 = A  + (size_t)(m0+srow   )*K + scol;
  const u16* gA1 = A  + (size_t)(m0+srow+64)*K + scol;
  const u16* gB0 = Bt + (size_t)(n0+srow   )*K + scol;
  const u16* gB1 = Bt + (size_t)(n0+srow+64)*K + scol;

  f32x4 acc[4][4] = {};
  const int lr = lane&15, lk = (lane>>4)<<3;
  const int rdo = lk ^ ((lr&3)<<3);

  const int NIT = Klen>>5;   // >= 3 required (all launches satisfy)
  STG4(0, kbeg);
  STG4(1, kbeg+32);
  STG4(2, kbeg+64);

  for (int it=0; it<NIT-2; ++it){
    const int b = it - (it/3)*3;
    waitv<8>();
    __builtin_amdgcn_s_barrier();
    const u16* baseA = lds + b*4096;
    const u16* baseB = lds + 12288 + b*4096;
    s16x8 af[4], bfr[4];
    #pragma unroll
    for(int m=0;m<4;m++) af[m]  = *(const s16x8*)(baseA + ((wr<<6)+(m<<4)+lr)*32 + rdo);
    #pragma unroll
    for(int n=0;n<4;n++) bfr[n] = *(const s16x8*)(baseB + ((wc<<6)+(n<<4)+lr)*32 + rdo);
    asm volatile("s_waitcnt lgkmcnt(0)" ::: "memory");
    __builtin_amdgcn_sched_barrier(0);
    __builtin_amdgcn_s_barrier();
    if (it+3 < NIT) STG4(b, kbeg + ((it+3)<<5));
    #pragma unroll
    for(int m=0;m<4;m++)
      #pragma unroll
      for(int n=0;n<4;n++)
        acc[m][n] = __builtin_amdgcn_mfma_f32_16x16x32_bf16(af[m], bfr[n], acc[m][n], 0,0,0);
  }
  {
    const int it = NIT-2; const int b = it - (it/3)*3;
    waitv<4>();
    __builtin_amdgcn_s_barrier();
    const u16* baseA = lds + b*4096;
    const u16* baseB = lds + 12288 + b*4096;
    s16x8 af[4], bfr[4];
    #pragma unroll
    for(int m=0;m<4;m++) af[m]  = *(const s16x8*)(baseA + ((wr<<6)+(m<<4)+lr)*32 + rdo);
    #pragma unroll
    for(int n=0;n<4;n++) bfr[n] = *(const s16x8*)(baseB + ((wc<<6)+(n<<4)+lr)*32 + rdo);
    #pragma unroll
    for(int m=0;m<4;m++)
      #pragma unroll
      for(int n=0;n<4;n++)
        acc[m][n] = __builtin_amdgcn_mfma_f32_16x16x32_bf16(af[m], bfr[n], acc[m][n], 0,0,0);
  }
  {
    const int it = NIT-1; const int b = it - (it/3)*3;
    waitv<0>();
    __builtin_amdgcn_s_barrier();
    const u16* baseA = lds + b*4096;
    const u16* baseB = lds + 12288 + b*4096;
    s16x8 af[4], bfr[4];
    #pragma unroll
    for(int m=0;m<4;m++) af[m]  = *(const s16x8*)(baseA + ((wr<<6)+(m<<4)+lr)*32 + rdo);
    #pragma unroll
    for(int n=0;n<4;n++) bfr[n] = *(const s16x8*)(baseB + ((wc<<6)+(n<<4)+lr)*32 + rdo);
    #pragma unroll
    for(int m=0;m<4;m++)
      #pragma unroll
      for(int n=0;n<4;n++)
        acc[m][n] = __builtin_amdgcn_mfma_f32_16x16x32_bf16(af[m], bfr[n], acc[m][n], 0,0,0);
  }

  float tmin = 3.0e38f, tmax = -3.0e38f;
  if (MODE==1){
    #pragma unroll
    for(int m=0;m<4;m++)
      #pragma unroll
      for(int n=0;n<4;n++){
        f32x4 v = acc[m][n];
        #pragma unroll
        for(int e=0;e<4;e++){ tmin = fminf(tmin,v[e]); tmax = fmaxf(tmax,v[e]); }
      }
  }

  __syncthreads();
  u16* lC = lds;
  {
    const int rb_l = (wr<<6) + ((lane>>4)<<2);
    const int cb_l = (wc<<6) + lr;
    #pragma unroll
    for(int m=0;m<4;m++)
      #pragma unroll
      for(int n=0;n<4;n++){
        f32x4 v = acc[m][n];
        #pragma unroll
        for(int e=0;e<4;e++)
          lC[(rb_l+(m<<4)+e)*128 + cb_l+(n<<4)] = f2b(v[e]);
      }
  }
  __syncthreads();
  u16* Cp = (MODE==0) ? (Cb + (size_t)blockIdx.z * M * Nc) : Cb;
  #pragma unroll
  for(int q=0;q<8;q++){
    int c = (q<<8) + tid;
    int r = c>>4, cc = (c&15)<<3;
    s16x8 v = *(const s16x8*)(lC + r*128 + cc);
    if (MODE==1)
      __builtin_nontemporal_store(v, (s16x8*)(Cp + (size_t)(m0+r)*Nc + n0 + cc));
    else
      *(s16x8*)(Cp + (size_t)(m0+r)*Nc + n0 + cc) = v;
  }

  if (MODE==1){
    tmin = wave_min(tmin); tmax = wave_max(tmax);
    __shared__ float rmn[4], rmx[4];
    if(lane==0){ rmn[wid]=tmin; rmx[wid]=tmax; }
    __syncthreads();
    if(tid==0){
      float mn=fminf(fminf(rmn[0],rmn[1]),fminf(rmn[2],rmn[3]));
      float mx=fmaxf(fmaxf(rmx[0],rmx[1]),fmaxf(rmx[2],rmx[3]));
      atomicMin(mmx+0, fkey(mn));
      atomicMax(mmx+1, fkey(mx));
    }
  }
}

// src [R][C] fp32 -> dst [C][R] bf16   (weight prep; dst may be a sub-block base)
__global__ __launch_bounds__(256) void transpose_cast(
  const float* __restrict__ src, u16* __restrict__ dst, int R, int C)
{
  __shared__ float t[32][33];
  int c0 = blockIdx.x<<5, r0 = blockIdx.y<<5;
  int tx = threadIdx.x&31, ty = threadIdx.x>>5;
  #pragma unroll
  for(int i=0;i<32;i+=8) t[ty+i][tx] = src[(size_t)(r0+ty+i)*C + c0+tx];
  __syncthreads();
  #pragma unroll
  for(int i=0;i<32;i+=8) dst[(size_t)(c0+ty+i)*R + r0+tx] = f2b(t[tx][ty+i]);
}

// dst[C][R] bf16 = transpose( sum_p bf16_plane_p [R][C] ); gated (dense path)
__global__ __launch_bounds__(256) void transpose_sum_bf(
  const u16* __restrict__ src, size_t pstr, int nsp,
  u16* __restrict__ dst, int R, int C, const unsigned* __restrict__ gate)
{
  if (gate && gate[2] <= SPARSE_MAX) return;
  __shared__ float t[32][33];
  int c0 = blockIdx.x<<5, r0 = blockIdx.y<<5;
  int tx = threadIdx.x&31, ty = threadIdx.x>>5;
  #pragma unroll
  for(int i=0;i<32;i+=8){
    float v = 0;
    for(int p=0;p<nsp;p++)
      v += b2f(src[(size_t)p*pstr + (size_t)(r0+ty+i)*C + c0+tx]);
    t[ty+i][tx] = v;
  }
  __syncthreads();
  #pragma unroll
  for(int i=0;i<32;i+=8) dst[(size_t)(c0+ty+i)*R + r0+tx] = f2b(t[tx][ty+i]);
}

__global__ __launch_bounds__(256) void prep_x(const float* __restrict__ x,
  u16* __restrict__ xb, u16* __restrict__ xnb)
{
  int row = blockIdx.x, t = threadIdx.x;
  const float* p = x + (size_t)row*L_ + (t<<2);
  f32x4 v = *(const f32x4*)p;
  float ss = v[0]*v[0]+v[1]*v[1]+v[2]*v[2]+v[3]*v[3];
  float tot = blk_sum256(ss);
  float inv = 1.0f/fmaxf(sqrtf(tot), 1e-12f);
  u16* pb = xb  + (size_t)row*L_ + (t<<2);
  u16* pn = xnb + (size_t)row*L_ + (t<<2);
  #pragma unroll
  for(int k=0;k<4;k++){ pb[k]=f2b(v[k]); pn[k]=f2b(v[k]*inv); }
}

// fused-projection epilogue: a at cols [0,256), b at [256,512) of [N,1536] planes
__global__ __launch_bounds__(256) void attn_epi(const u16* __restrict__ SPA,
  size_t pstr, int nsp,
  const float* __restrict__ ba, const float* __restrict__ bb,
  const float* __restrict__ wc, const float* __restrict__ bc,
  float* __restrict__ agg, float* __restrict__ s)
{
  int row = (blockIdx.x<<2) + (threadIdx.x>>6);
  int lane = threadIdx.x&63;
  float a[4]={0,0,0,0}, b[4]={0,0,0,0};
  for(int p=0;p<nsp;p++){
    s16x4 ua = *(const s16x4*)(SPA + (size_t)p*pstr + (size_t)row*1536 + (lane<<2));
    s16x4 ub = *(const s16x4*)(SPA + (size_t)p*pstr + (size_t)row*1536 + 256 + (lane<<2));
    #pragma unroll
    for(int j=0;j<4;j++){ a[j]+=b2f((u16)ua[j]); b[j]+=b2f((u16)ub[j]); }
  }
  float acc=0;
  #pragma unroll
  for(int j=0;j<4;j++){
    int h = (lane<<2)+j;
    float tv = tanhf(a[j]+ba[h]);
    float sg = 1.0f/(1.0f+expf(-(b[j]+bb[h])));
    acc += tv*sg*wc[h];
  }
  acc = wave_sum(acc);
  if(lane==0){
    float v = acc + bc[0];
    agg[row]=v;
    s[row]=1.0f/(1.0f+expf(-v));
  }
}

__global__ __launch_bounds__(256) void s_stats(const float* __restrict__ s, float* __restrict__ sc){
  int t=threadIdx.x;
  float sum=0, mn=3e38f, mx=-3e38f;
  for(int i=t;i<N_;i+=256){ float v=s[i]; sum+=v; mn=fminf(mn,v); mx=fmaxf(mx,v); }
  float S=blk_sum256(sum);
  float MN=blk_min256(mn);
  float MX=blk_max256(mx);
  if(t==0){ sc[0]=S; sc[1]=MN; sc[2]=MX; }
}

__global__ __launch_bounds__(256) void aw_write(const float* __restrict__ maps, const float* __restrict__ s,
  const float* __restrict__ sc, u16* __restrict__ awb)
{
  int i = blockIdx.x, t = threadIdx.x;
  float smin = sc[1], smax = sc[2];
  float mn = smin*smin, mx = smax*smax;
  float beta = 0.6f/(mx-mn);
  float c1 = 0.4f - beta*mn;
  float si = s[i];
  const float* mrow = maps + (size_t)i*N_;
  float mv[24];
  float part = 0;
  #pragma unroll
  for(int q=0;q<24;q++){
    int j = t + (q<<8);
    mv[q] = c1 + beta*si*s[j] + mrow[j];
    part += mv[q];
  }
  float r = blk_sum256(part);
  float inv = 1.0f/fmaxf(r, 1e-12f);
  u16* orow = awb + (size_t)i*N_;
  #pragma unroll
  for(int q=0;q<24;q++)
    __builtin_nontemporal_store(f2b(mv[q]*inv), orow + t + (q<<8));
}

// out = relu(LN( (sum_p Y_p)*rowscale + bias )).  If gate says sparse, read
// Yalt ([N,512], 1 plane) instead of Y.
__global__ __launch_bounds__(256) void ln_epi512(const u16* __restrict__ Y, size_t pstr, int nsp,
  int rs, int cbase,
  const float* __restrict__ ki,
  const float* __restrict__ bias, const float* __restrict__ g, const float* __restrict__ bn,
  u16* __restrict__ outb,
  const unsigned* __restrict__ gate, const u16* __restrict__ Yalt)
{
  const u16* src = Y; size_t ps = pstr; int np = nsp, rstride = rs, cb = cbase;
  if (gate && gate[2] <= SPARSE_MAX){ src = Yalt; ps = 0; np = 1; rstride = 512; cb = 0; }
  int row = (blockIdx.x<<2)+(threadIdx.x>>6);
  int lane = threadIdx.x&63;
  int c0 = lane<<3;
  float v[8] = {0,0,0,0,0,0,0,0};
  for(int p=0;p<np;p++){
    s16x8 u = *(const s16x8*)(src + (size_t)p*ps + (size_t)row*rstride + cb + c0);
    #pragma unroll
    for(int j=0;j<8;j++) v[j] += b2f((u16)u[j]);
  }
  float scale = ki ? (1.0f/ki[row]) : 1.0f;
  float sum=0, ssum=0;
  #pragma unroll
  for(int j=0;j<8;j++){ v[j] = v[j]*scale + bias[c0+j]; sum+=v[j]; ssum+=v[j]*v[j]; }
  sum = wave_sum(sum); ssum = wave_sum(ssum);
  float m = sum*(1.0f/D_);
  float var = ssum*(1.0f/D_) - m*m;
  float invsd = rsqrtf(var + 1e-5f);
  u16 ob[8];
  #pragma unroll
  for(int j=0;j<8;j++){
    float o = (v[j]-m)*invsd*g[c0+j] + bn[c0+j];
    o = fmaxf(o, 0.0f);
    ob[j] = f2b(o);
  }
  *(s16x8*)(outb + (size_t)row*D_ + c0) = *(s16x8*)ob;
}

__global__ __launch_bounds__(256) void bias_cast(const u16* __restrict__ Y, size_t pstr, int nsp,
  const float* __restrict__ b, u16* __restrict__ outb)
{
  size_t idx = ((size_t)blockIdx.x*256 + threadIdx.x)<<3;
  float v[8] = {0,0,0,0,0,0,0,0};
  for(int p=0;p<nsp;p++){
    s16x8 u = *(const s16x8*)(Y + (size_t)p*pstr + idx);
    #pragma unroll
    for(int j=0;j<8;j++) v[j] += b2f((u16)u[j]);
  }
  int c = (int)(idx & (D_-1));
  u16 ob[8];
  #pragma unroll
  for(int k=0;k<8;k++) ob[k] = f2b(v[k]+b[c+k]);
  *(s16x8*)(outb+idx) = *(s16x8*)ob;
}

__global__ void init_k(unsigned* mmx){ mmx[0]=0xFFFFFFFFu; mmx[1]=0u; mmx[2]=0u; }

// binarize in place + bitmap + per-row count + max-nnz + fused trans/z
__global__ __launch_bounds__(256) void binarize(u16* __restrict__ csb,
  unsigned* __restrict__ mmx, const float* __restrict__ agg,
  float* __restrict__ ki, float* __restrict__ z, u64* __restrict__ bm)
{
  int i = blockIdx.x, t = threadIdx.x;
  int lane = t&63, w = t>>6;
  float mn = funkey(mmx[0]), mx = funkey(mmx[1]);
  float th = mn + 0.5f*(mx-mn);
  u16* row = csb + (size_t)i*N_;
  u64* bmrow = bm + (size_t)i*96;
  float cnt = 0, dot = 0;
  #pragma unroll
  for(int q=0;q<24;q++){
    int j = t + (q<<8);
    bool on = b2f(row[j]) >= th;
    __builtin_nontemporal_store(on ? (u16)0x3F80 : (u16)0, row + j);
    u64 mask = __ballot(on);
    if(lane==0) bmrow[(q<<2)+w] = mask;
    if(on){ cnt += 1.0f; dot += agg[j]; }
  }
  float k = blk_sum256(cnt);
  float dt = blk_sum256(dot);
  if(t==0){
    ki[i] = k;
    float tr = dt/(k*sqrtf((float)N_));
    z[i] = 0.3f*tr + 0.7f*agg[i];
    atomicMax(mmx+2, (unsigned)(k+0.5f));
  }
}

// sparse adjacency apply: YS[i,:] = sum_{j: bit set} sum_p SP[p][j,:]
__global__ __launch_bounds__(256) void gather_rows(const u64* __restrict__ bm,
  const u16* __restrict__ SPp, size_t pstr, int nsp,
  const unsigned* __restrict__ gate, u16* __restrict__ YS)
{
  if (gate[2] > SPARSE_MAX) return;
  int i = blockIdx.x, t = threadIdx.x;
  __shared__ u64 wbuf[96];
  __shared__ u16 idx[SPARSE_MAX];
  __shared__ int nn_s;
  if (t < 96) wbuf[t] = bm[(size_t)i*96 + t];
  __syncthreads();
  if (t == 0){
    int nn = 0;
    for(int k=0;k<96;k++){
      u64 m = wbuf[k];
      while(m && nn < (int)SPARSE_MAX){
        int b = __ffsll((long long)m) - 1;
        m &= m - 1;
        idx[nn++] = (u16)((k<<6) + b);
      }
    }
    nn_s = nn;
  }
  __syncthreads();
  int nn = nn_s;
  float a0=0, a1=0;
  for(int k=0;k<nn;k++){
    size_t jb = (size_t)idx[k]*512;
    for(int p=0;p<nsp;p++){
      a0 += b2f(SPp[p*pstr + jb + t]);
      a1 += b2f(SPp[p*pstr + jb + t + 256]);
    }
  }
  YS[(size_t)i*512 + t]       = f2b(a0);
  YS[(size_t)i*512 + t + 256] = f2b(a1);
}

__global__ __launch_bounds__(1024) void softmax_prep(const float* __restrict__ z,
  float* __restrict__ e, float* __restrict__ sexp)
{
  int t = threadIdx.x;
  __shared__ float sm[16];
  float mx=-3e38f;
  for(int i=t;i<N_;i+=1024) mx=fmaxf(mx,z[i]);
  mx = wave_max(mx);
  if((t&63)==0) sm[t>>6]=mx;
  __syncthreads();
  float zm = sm[0];
  #pragma unroll
  for(int w=1;w<16;w++) zm=fmaxf(zm,sm[w]);
  __syncthreads();
  float sum=0;
  for(int i=t;i<N_;i+=1024){ float ee=expf(z[i]-zm); e[i]=ee; sum+=ee; }
  sum = wave_sum(sum);
  if((t&63)==0) sm[t>>6]=sum;
  __syncthreads();
  if(t==0){ float S=0; for(int w=0;w<16;w++) S+=sm[w]; *sexp=S; }
}

__global__ __launch_bounds__(256) void pooled_partial(const float* __restrict__ e,
  const u16* __restrict__ g2b, const u16* __restrict__ g1b, float* __restrict__ part)
{
  int b = blockIdx.x, t = threadIdx.x;
  float a0=0,a1=0,a2=0,a3=0;
  for(int r=0;r<24;r++){
    int row = b*24+r;
    float w = e[row];
    a0 += w * b2f(g2b[(size_t)row*D_ + t]);
    a1 += w * b2f(g2b[(size_t)row*D_ + t+256]);
    a2 += w * b2f(g1b[(size_t)row*D_ + t]);
    a3 += w * b2f(g1b[(size_t)row*D_ + t+256]);
  }
  part[(size_t)b*1024 + t]      = a0;
  part[(size_t)b*1024 + t+256]  = a1;
  part[(size_t)b*1024 + t+512]  = a2;
  part[(size_t)b*1024 + t+768]  = a3;
}

__global__ __launch_bounds__(1024) void final_k(const float* __restrict__ part, const float* __restrict__ sexp,
  const float* __restrict__ lng, const float* __restrict__ lnb,
  const float* __restrict__ clsw, float* __restrict__ out)
{
  int t = threadIdx.x;
  __shared__ float red[16];
  __shared__ float smv[1024];
  __shared__ float lgs[4];
  float p=0;
  for(int b=0;b<256;b++) p += part[b*1024 + t];
  p /= sexp[0];
  float w = wave_sum(p);
  if((t&63)==0) red[t>>6]=w;
  __syncthreads();
  float tot=0;
  #pragma unroll
  for(int i2=0;i2<16;i2++) tot+=red[i2];
  float m = tot*(1.0f/1024.0f);
  __syncthreads();
  float d = p-m;
  w = wave_sum(d*d);
  if((t&63)==0) red[t>>6]=w;
  __syncthreads();
  tot=0;
  #pragma unroll
  for(int i2=0;i2<16;i2++) tot+=red[i2];
  float var = tot*(1.0f/1024.0f);
  float y = d*rsqrtf(var+1e-5f)*lng[t] + lnb[t];
  smv[t]=y;
  __syncthreads();
  if(t<4){
    float lg=0;
    for(int j=0;j<1024;j++) lg += smv[j]*clsw[j*4+t];
    lgs[t]=lg;
  }
  __syncthreads();
  if(t==0){
    float h[4];
    int am=0; float best=lgs[0];
    #pragma unroll
    for(int c2=0;c2<4;c2++){ h[c2]=1.0f/(1.0f+expf(-lgs[c2])); if(lgs[c2]>best){best=lgs[c2];am=c2;} }
    float sv=1.0f;
    #pragma unroll
    for(int c2=0;c2<4;c2++){ out[c2]=h[c2]; sv*=(1.0f-h[c2]); out[4+c2]=sv; }
    out[8]=(float)am;
  }
}

extern "C" void kernel_launch(void* const* d_in, const int* in_sizes, int n_in,
                              void* d_out, int out_size, void* d_ws, size_t ws_size,
                              hipStream_t stream)
{
  const float* x_path =(const float*)d_in[0];
  const float* maps   =(const float*)d_in[1];
  const float* nl0_w1 =(const float*)d_in[2];
  const float* nl0_b1 =(const float*)d_in[3];
  const float* nl0_g  =(const float*)d_in[4];
  const float* nl0_bn =(const float*)d_in[5];
  const float* nl0_w2 =(const float*)d_in[6];
  const float* nl0_b2 =(const float*)d_in[7];
  const float* nl1_w1 =(const float*)d_in[8];
  const float* nl1_b1 =(const float*)d_in[9];
  const float* nl1_g  =(const float*)d_in[10];
  const float* nl1_bn =(const float*)d_in[11];
  const float* nl1_w2 =(const float*)d_in[12];
  const float* nl1_b2 =(const float*)d_in[13];
  const float *gw[6], *gb[6], *gg[6], *gbn[6];   // gc0,gc1,gc2,ga0,ga1,ga2
  for(int l=0;l<6;l++){
    gw[l]  = (const float*)d_in[14+l*4+0];
    gb[l]  = (const float*)d_in[14+l*4+1];
    gg[l]  = (const float*)d_in[14+l*4+2];
    gbn[l] = (const float*)d_in[14+l*4+3];
  }
  const float* attn_wa=(const float*)d_in[38];
  const float* attn_ba=(const float*)d_in[39];
  const float* attn_wb=(const float*)d_in[40];
  const float* attn_bb=(const float*)d_in[41];
  const float* attn_wc=(const float*)d_in[42];
  const float* attn_bc=(const float*)d_in[43];
  const float* cls_w  =(const float*)d_in[44];
  const float* ln_g   =(const float*)d_in[45];
  const float* ln_b   =(const float*)d_in[46];

  char* ws=(char*)d_ws;
  size_t off=0;
  auto alc=[&](size_t b)->char*{ char* p=ws+off; off=(off+b+255)&~(size_t)255; return p; };
  u16* BIG = (u16*)alc((size_t)N_*N_*2);          // aw, then cs/binary (time-shared)
  u16* XB  = (u16*)alc((size_t)N_*L_*2);
  u16* XNB = (u16*)alc((size_t)N_*L_*2);
  u16* WT_proj=(u16*)alc((size_t)1536*L_*2);      // [wa;wb;nl0w1;nl1w1] transposed
  u16* WT_nl0w2=(u16*)alc((size_t)D_*D_*2);
  u16* WT_nl1w2=(u16*)alc((size_t)D_*D_*2);
  u16* WT_g[6];
  for(int l=0;l<6;l++) WT_g[l]=(u16*)alc((size_t)D_*D_*2);
  u16* SP = (u16*)alc((size_t)2*N_*1536*2);       // split planes (max: proj SK=2)
  u16* XWT=(u16*)alc((size_t)D_*N_*2);
  u16* XA0=(u16*)alc((size_t)N_*D_*2);
  u16* XA1=(u16*)alc((size_t)N_*D_*2);
  u16* X0B=(u16*)alc((size_t)N_*D_*2);
  u16* X1B=(u16*)alc((size_t)N_*D_*2);
  u16* YS =(u16*)alc((size_t)N_*D_*2);
  u64* BM =(u64*)alc((size_t)N_*96*8);
  float* PART=(float*)alc((size_t)256*1024*4);
  float* AGG=(float*)alc(N_*4);
  float* SS =(float*)alc(N_*4);
  float* KI =(float*)alc(N_*4);
  float* Z  =(float*)alc(N_*4);
  float* E  =(float*)alc(N_*4);
  float* SC =(float*)alc(256);
  unsigned* MMX=(unsigned*)alc(256);
  float* SEXP=(float*)alc(256);

  const size_t PS_D = (size_t)N_*D_;      // 512-col plane stride
  const size_t PS_P = (size_t)N_*1536;    // proj plane stride

  init_k<<<1,1,0,stream>>>(MMX);
  prep_x<<<N_,256,0,stream>>>(x_path, XB, XNB);

  // weight prep: WT_proj rows [0,256)=wa^T, [256,512)=wb^T, [512,1024)=nl0w1^T, [1024,1536)=nl1w1^T
  transpose_cast<<<dim3(H_/32, L_/32),256,0,stream>>>(attn_wa, WT_proj,                         L_, H_);
  transpose_cast<<<dim3(H_/32, L_/32),256,0,stream>>>(attn_wb, WT_proj + (size_t)256*L_,        L_, H_);
  transpose_cast<<<dim3(D_/32, L_/32),256,0,stream>>>(nl0_w1,  WT_proj + (size_t)512*L_,        L_, D_);
  transpose_cast<<<dim3(D_/32, L_/32),256,0,stream>>>(nl1_w1,  WT_proj + (size_t)1024*L_,       L_, D_);
  transpose_cast<<<dim3(D_/32, D_/32),256,0,stream>>>(nl0_w2, WT_nl0w2, D_, D_);
  transpose_cast<<<dim3(D_/32, D_/32),256,0,stream>>>(nl1_w2, WT_nl1w2, D_, D_);
  for(int l=0;l<6;l++)
    transpose_cast<<<dim3(D_/32, D_/32),256,0,stream>>>(gw[l], WT_g[l], D_, D_);

  // fused X projections: [a|b|h0|h1] = XB @ WT_proj^T  (SK=2)
  gemm_bt<0><<<dim3(1536/128, N_/128, 2),256,0,stream>>>(XB, WT_proj, N_, 1536, L_, SP, nullptr, nullptr);
  attn_epi<<<N_/4,256,0,stream>>>(SP, PS_P, 2, attn_ba, attn_bb, attn_wc, attn_bc, AGG, SS);
  s_stats<<<1,256,0,stream>>>(SS,SC);
  aw_write<<<N_,256,0,stream>>>(maps,SS,SC,BIG);

  // x1 = relu(LN(h1)) @ w2 + b2
  ln_epi512<<<N_/4,256,0,stream>>>(SP,PS_P,2, 1536,1024, nullptr, nl1_b1,nl1_g,nl1_bn, XA1, nullptr,nullptr);
  // x0 = relu(LN(h0)) @ w2 + b2   (ln now; gemm later to keep SP free order simple)
  ln_epi512<<<N_/4,256,0,stream>>>(SP,PS_P,2, 1536, 512, nullptr, nl0_b1,nl0_g,nl0_bn, XA0, nullptr,nullptr);

  gemm_bt<0><<<dim3(D_/128,N_/128,4),256,0,stream>>>(XA1, WT_nl1w2, N_,D_,D_, SP, nullptr, nullptr);
  bias_cast<<<(N_*D_/8)/256,256,0,stream>>>(SP,PS_D,4, nl1_b2, X1B);

  // ga chain (dense adjacency = BIG = aw)
  {
    const u16* cur=X1B;
    for(int l=0;l<3;l++){
      int gi = 3+l;
      gemm_bt<0><<<dim3(D_/128,N_/128,4),256,0,stream>>>(cur, WT_g[gi], N_,D_,D_, SP, nullptr, nullptr);
      transpose_sum_bf<<<dim3(D_/32, N_/32),256,0,stream>>>(SP, PS_D, 4, XWT, N_, D_, nullptr);
      gemm_bt<0><<<dim3(D_/128,N_/128,4),256,0,stream>>>(BIG, XWT, N_,D_,N_, SP, nullptr, nullptr);
      u16* nxt = (l==0)? XA1 : (l==1)? YS : X1B;
      ln_epi512<<<N_/4,256,0,stream>>>(SP,PS_D,4, 512,0, nullptr, gb[gi],gg[gi],gbn[gi], nxt, nullptr,nullptr);
      cur = nxt;
    }
  }

  gemm_bt<0><<<dim3(D_/128,N_/128,4),256,0,stream>>>(XA0, WT_nl0w2, N_,D_,D_, SP, nullptr, nullptr);
  bias_cast<<<(N_*D_/8)/256,256,0,stream>>>(SP,PS_D,4, nl0_b2, X0B);

  // cosine gram -> BIG (NT bf16) + min/max; binarize (+bitmap, max-nnz, fused trans/z)
  gemm_bt<1><<<dim3(N_/128,N_/128,1),256,0,stream>>>(XNB, XNB, N_,N_,L_, BIG, MMX, nullptr);
  binarize<<<N_,256,0,stream>>>(BIG, MMX, AGG, KI, Z, BM);

  // gc chain: sparse gather path (gated) with dense GEMM fallback
  {
    const u16* cur=X0B;
    for(int l=0;l<3;l++){
      int gi = l;
      gemm_bt<0><<<dim3(D_/128,N_/128,4),256,0,stream>>>(cur, WT_g[gi], N_,D_,D_, SP, nullptr, nullptr);
      transpose_sum_bf<<<dim3(D_/32, N_/32),256,0,stream>>>(SP, PS_D, 4, XWT, N_, D_, MMX);
      gemm_bt<0><<<dim3(D_/128,N_/128,4),256,0,stream>>>(BIG, XWT, N_,D_,N_, SP, nullptr, MMX);
      gather_rows<<<N_,256,0,stream>>>(BM, SP, PS_D, 4, MMX, YS);
      u16* nxt = (l==0)? XA1 : (l==1)? XA0 : X0B;
      ln_epi512<<<N_/4,256,0,stream>>>(SP,PS_D,4, 512,0, KI, gb[gi],gg[gi],gbn[gi], nxt, MMX, YS);
      cur = nxt;
    }
  }

  // pooling + head
  softmax_prep<<<1,1024,0,stream>>>(Z,E,SEXP);
  pooled_partial<<<256,256,0,stream>>>(E,X1B,X0B,PART);
  final_k<<<1,1024,0,stream>>>(PART,SEXP,ln_g,ln_b,cls_w,(float*)d_out);

  (void)in_sizes;(void)n_in;(void)out_size;(void)ws_size;
}